// Round 3
// baseline (2612.707 us; speedup 1.0000x reference)
//
#include <hip/hip_runtime.h>

typedef unsigned short u16;

#define S_LEN 2048
#define HID   2048
#define NH    32
#define NKV   8
#define HD    64
#define DVV   128
#define LAMBDA_INIT  0.7455692280263525f
#define ONE_MINUS_LI 0.2544307719736475f

// C[m][n] = sum_k A[m*K+k] * B[n*K+k]   (A,B fp32; C fp32)
__global__ __launch_bounds__(256) void gemm_nt(const float* __restrict__ A, const float* __restrict__ B,
                                               float* __restrict__ C, int M, int N, int K)
{
  __shared__ __attribute__((aligned(16))) float As[16][68];
  __shared__ __attribute__((aligned(16))) float Bs[16][68];
  const int t  = threadIdx.x;
  const int m0 = blockIdx.y * 64, n0 = blockIdx.x * 64;
  const int lr = t >> 2;           // 0..63 row within tile
  const int lq = (t & 3) * 4;      // k sub-offset 0,4,8,12
  const int tm = (t >> 4) * 4;     // microtile row base
  const int tn = (t & 15) * 4;     // microtile col base
  float acc[4][4] = {{0.f}};
  const float* Aptr = A + (size_t)(m0 + lr) * K + lq;
  const float* Bptr = B + (size_t)(n0 + lr) * K + lq;
  for (int k0 = 0; k0 < K; k0 += 16){
    float4 av = *(const float4*)(Aptr + k0);
    float4 bv = *(const float4*)(Bptr + k0);
    __syncthreads();
    As[lq+0][lr] = av.x; As[lq+1][lr] = av.y;
    As[lq+2][lr] = av.z; As[lq+3][lr] = av.w;
    Bs[lq+0][lr] = bv.x; Bs[lq+1][lr] = bv.y;
    Bs[lq+2][lr] = bv.z; Bs[lq+3][lr] = bv.w;
    __syncthreads();
#pragma unroll
    for (int kk = 0; kk < 16; kk++){
      float a0 = As[kk][tm+0], a1 = As[kk][tm+1], a2 = As[kk][tm+2], a3 = As[kk][tm+3];
      float b0 = Bs[kk][tn+0], b1 = Bs[kk][tn+1], b2 = Bs[kk][tn+2], b3 = Bs[kk][tn+3];
      acc[0][0] += a0*b0; acc[0][1] += a0*b1; acc[0][2] += a0*b2; acc[0][3] += a0*b3;
      acc[1][0] += a1*b0; acc[1][1] += a1*b1; acc[1][2] += a1*b2; acc[1][3] += a1*b3;
      acc[2][0] += a2*b0; acc[2][1] += a2*b1; acc[2][2] += a2*b2; acc[2][3] += a2*b3;
      acc[3][0] += a3*b0; acc[3][1] += a3*b1; acc[3][2] += a3*b2; acc[3][3] += a3*b3;
    }
  }
#pragma unroll
  for (int i = 0; i < 4; i++)
#pragma unroll
    for (int j = 0; j < 4; j++)
      C[(size_t)(m0+tm+i)*N + (n0+tn+j)] = acc[i][j];
}

// in-place RoPE on X laid out (S, nh*64), fp32; cos/sin fp32 (S,64)
__global__ __launch_bounds__(256) void rope_kernel(float* __restrict__ X,
    const float* __restrict__ cosb, const float* __restrict__ sinb, int nh)
{
  int idx = blockIdx.x * 256 + threadIdx.x;   // (s, h, d<32)
  int d = idx & 31;
  int h = (idx >> 5) & (nh - 1);
  int s = idx / (32 * nh);
  float c1 = cosb[s * HD + d];
  float s1 = sinb[s * HD + d];
  float c2 = cosb[s * HD + d + 32];
  float s2 = sinb[s * HD + d + 32];
  size_t base = (size_t)s * ((size_t)nh * HD) + (size_t)h * HD + d;
  float x1 = X[base], x2 = X[base + 32];
  X[base]      = x1 * c1 - x2 * s1;
  X[base + 32] = x2 * c2 + x1 * s2;
}

#define BQ 64
#define BK 32

// Q (S, 32*64) fp32 post-rope; K,V (S, 8*64) fp32; Att out (32, S, 128) fp32
__global__ __launch_bounds__(256) void attn_kernel(const float* __restrict__ Q,
                                                   const float* __restrict__ K,
                                                   const float* __restrict__ V,
                                                   float* __restrict__ Att)
{
  __shared__ __attribute__((aligned(16))) float Qs[BQ][HD + 4];
  __shared__ __attribute__((aligned(16))) float Ks[BK][HD + 4];
  __shared__ __attribute__((aligned(16))) float Vs[BK][DVV + 4];
  __shared__ __attribute__((aligned(16))) float Ps[BQ][BK + 4];
  __shared__ float mS[BQ], lS[BQ], aS[BQ];

  const int h   = blockIdx.y;
  const int q0  = blockIdx.x * BQ;
  const int kvh = h >> 2;            // k head after GQA repeat
  const int c   = (h & 15) >> 2;     // v_cat = [v_kv[c], v_kv[c+4]]
  const int t   = threadIdx.x;

#pragma unroll
  for (int i = 0; i < 4; i++){       // Q tile 64x64
    int f4 = t + i * 256;
    int r  = f4 >> 4;
    int c4 = (f4 & 15) * 4;
    *(float4*)&Qs[r][c4] = *(const float4*)&Q[(size_t)(q0 + r) * HID + h * HD + c4];
  }
  if (t < BQ){ mS[t] = -3.0e38f; lS[t] = 0.f; }
  __syncthreads();

  const int r  = t >> 2;     // score row
  const int qq = t & 3;      // score col group
  const int rg = t >> 4;     // PV row group (rows rg*4..+3)
  const int cg = t & 15;     // PV col group (dims cg*8..+7)

  float4 qr[16];
#pragma unroll
  for (int i = 0; i < 16; i++) qr[i] = *(float4*)&Qs[r][i * 4];

  float4 o[4][2];
#pragma unroll
  for (int rr = 0; rr < 4; rr++){
    o[rr][0] = make_float4(0.f,0.f,0.f,0.f);
    o[rr][1] = make_float4(0.f,0.f,0.f,0.f);
  }

  const int kend = q0 + BQ;
  for (int k0 = 0; k0 < kend; k0 += BK){
    __syncthreads();
#pragma unroll
    for (int i = 0; i < 2; i++){     // K tile 32x64
      int f4 = t + i * 256;
      int kr = f4 >> 4;
      int c4 = (f4 & 15) * 4;
      *(float4*)&Ks[kr][c4] = *(const float4*)&K[(size_t)(k0 + kr) * (NKV*HD) + kvh * HD + c4];
    }
#pragma unroll
    for (int i = 0; i < 4; i++){     // V tile 32x128 (concat of two kv heads)
      int f4 = t + i * 256;
      int vr = f4 >> 5;
      int c4 = (f4 & 31) * 4;
      const float* src = (c4 < HD) ? &V[(size_t)(k0 + vr) * (NKV*HD) + c * HD + c4]
                                   : &V[(size_t)(k0 + vr) * (NKV*HD) + (c + 4) * HD + (c4 - HD)];
      *(float4*)&Vs[vr][c4] = *(const float4*)src;
    }
    __syncthreads();
    // scores: row r, cols qq*8..+7
#pragma unroll
    for (int jj = 0; jj < 8; jj++){
      int j = qq * 8 + jj;
      float4 s4 = make_float4(0.f,0.f,0.f,0.f);
#pragma unroll
      for (int i = 0; i < 16; i++){
        float4 kv = *(float4*)&Ks[j][i * 4];
        s4.x += qr[i].x * kv.x; s4.y += qr[i].y * kv.y;
        s4.z += qr[i].z * kv.z; s4.w += qr[i].w * kv.w;
      }
      float sv = (s4.x + s4.y + s4.z + s4.w) * 0.125f;
      Ps[r][j] = (k0 + j <= q0 + r) ? sv : -1.0e9f;
    }
    __syncthreads();
    // online softmax, one thread per row
    if (t < BQ){
      float mt = -3.0e38f;
#pragma unroll
      for (int j = 0; j < BK; j++) mt = fmaxf(mt, Ps[t][j]);
      float mold = mS[t];
      float mnew = fmaxf(mold, mt);
      float alpha = __expf(mold - mnew);
      float lsum = 0.f;
#pragma unroll
      for (int j = 0; j < BK; j++){
        float p = __expf(Ps[t][j] - mnew);
        Ps[t][j] = p;
        lsum += p;
      }
      mS[t] = mnew;
      lS[t] = alpha * lS[t] + lsum;
      aS[t] = alpha;
    }
    __syncthreads();
    // PV: o[rr][*] for rows rg*4+rr, dims cg*8..+7
    float al[4];
#pragma unroll
    for (int rr = 0; rr < 4; rr++) al[rr] = aS[rg * 4 + rr];
#pragma unroll
    for (int rr = 0; rr < 4; rr++){
      o[rr][0].x *= al[rr]; o[rr][0].y *= al[rr]; o[rr][0].z *= al[rr]; o[rr][0].w *= al[rr];
      o[rr][1].x *= al[rr]; o[rr][1].y *= al[rr]; o[rr][1].z *= al[rr]; o[rr][1].w *= al[rr];
    }
    for (int j4 = 0; j4 < 8; j4++){
      float p[4][4];
      *(float4*)p[0] = *(float4*)&Ps[rg*4+0][j4*4];
      *(float4*)p[1] = *(float4*)&Ps[rg*4+1][j4*4];
      *(float4*)p[2] = *(float4*)&Ps[rg*4+2][j4*4];
      *(float4*)p[3] = *(float4*)&Ps[rg*4+3][j4*4];
#pragma unroll
      for (int jj = 0; jj < 4; jj++){
        float4 v0 = *(float4*)&Vs[j4*4+jj][cg*8];
        float4 v1 = *(float4*)&Vs[j4*4+jj][cg*8+4];
#pragma unroll
        for (int rr = 0; rr < 4; rr++){
          float pp = p[rr][jj];
          o[rr][0].x += pp*v0.x; o[rr][0].y += pp*v0.y; o[rr][0].z += pp*v0.z; o[rr][0].w += pp*v0.w;
          o[rr][1].x += pp*v1.x; o[rr][1].y += pp*v1.y; o[rr][1].z += pp*v1.z; o[rr][1].w += pp*v1.w;
        }
      }
    }
  }
#pragma unroll
  for (int rr = 0; rr < 4; rr++){
    float li = 1.0f / lS[rg*4+rr];
    int srow = q0 + rg*4 + rr;
    float* dst = &Att[((size_t)h * S_LEN + srow) * DVV + cg * 8];
    float4 w0 = make_float4(o[rr][0].x*li, o[rr][0].y*li, o[rr][0].z*li, o[rr][0].w*li);
    float4 w1 = make_float4(o[rr][1].x*li, o[rr][1].y*li, o[rr][1].z*li, o[rr][1].w*li);
    *(float4*)dst = w0;
    *(float4*)(dst + 4) = w1;
  }
}

// a = att[h] - lam*att[h+16]; RMS-norm over 128; scale; write fp32 ctx (S, 16*128)
__global__ __launch_bounds__(128) void diff_rms(const float* __restrict__ Att,
    const float* __restrict__ lq1, const float* __restrict__ lk1,
    const float* __restrict__ lq2, const float* __restrict__ lk2,
    float* __restrict__ Ctx)
{
  __shared__ float lamS;
  __shared__ float red[2];
  const int blk = blockIdx.x;
  const int h = blk & 15;
  const int s = blk >> 4;
  const int d = threadIdx.x;   // 0..127
  if (d < 64){
    float p1 = lq1[d] * lk1[d];
    float p2 = lq2[d] * lk2[d];
#pragma unroll
    for (int off = 32; off; off >>= 1){
      p1 += __shfl_down(p1, off);
      p2 += __shfl_down(p2, off);
    }
    if (d == 0) lamS = __expf(p1) - __expf(p2) + LAMBDA_INIT;
  }
  __syncthreads();
  const float lam = lamS;
  float a = Att[((size_t)h * S_LEN + s) * DVV + d]
          - lam * Att[((size_t)(h+16) * S_LEN + s) * DVV + d];
  float ss = a * a;
#pragma unroll
  for (int off = 32; off; off >>= 1) ss += __shfl_down(ss, off);
  if ((d & 63) == 0) red[d >> 6] = ss;
  __syncthreads();
  float tot = red[0] + red[1];
  float rinv = rsqrtf(tot * (1.0f/128.0f) + 1e-6f);
  Ctx[(size_t)s * HID + h * DVV + d] = ONE_MINUS_LI * a * rinv;
}

extern "C" void kernel_launch(void* const* d_in, const int* in_sizes, int n_in,
                              void* d_out, int out_size, void* d_ws, size_t ws_size,
                              hipStream_t stream)
{
  (void)in_sizes; (void)n_in; (void)out_size; (void)ws_size;
  const float* hs   = (const float*)d_in[0];
  const float* cosb = (const float*)d_in[1];
  const float* sinb = (const float*)d_in[2];
  const float* Wq   = (const float*)d_in[3];
  const float* Wk   = (const float*)d_in[4];
  const float* Wv   = (const float*)d_in[5];
  const float* Wo   = (const float*)d_in[6];
  const float* lq1  = (const float*)d_in[7];
  const float* lk1  = (const float*)d_in[8];
  const float* lq2  = (const float*)d_in[9];
  const float* lk2  = (const float*)d_in[10];

  char* ws = (char*)d_ws;
  float* Qb  = (float*)(ws);                         // 16 MB  (S x 2048)
  float* Kb  = (float*)(ws + (16u << 20));           // 4 MB   (S x 512)
  float* Vb  = (float*)(ws + (20u << 20));           // 4 MB   (S x 512)
  float* Att = (float*)(ws + (24u << 20));           // 32 MB  (32 x S x 128)
  float* Ctx = (float*)(ws);                         // 16 MB, overlays Qb (Q dead after attn)

  gemm_nt<<<dim3(32, 32), 256, 0, stream>>>(hs, Wq, Qb, S_LEN, 2048, HID);
  gemm_nt<<<dim3(8, 32), 256, 0, stream>>>(hs, Wk, Kb, S_LEN, 512, HID);
  gemm_nt<<<dim3(8, 32), 256, 0, stream>>>(hs, Wv, Vb, S_LEN, 512, HID);
  rope_kernel<<<8192, 256, 0, stream>>>(Qb, cosb, sinb, NH);
  rope_kernel<<<2048, 256, 0, stream>>>(Kb, cosb, sinb, NKV);
  attn_kernel<<<dim3(S_LEN / BQ, NH), 256, 0, stream>>>(Qb, Kb, Vb, Att);
  diff_rms<<<16 * S_LEN, 128, 0, stream>>>(Att, lq1, lk1, lq2, lk2, Ctx);
  gemm_nt<<<dim3(32, 32), 256, 0, stream>>>(Ctx, Wo, (float*)d_out, S_LEN, 2048, HID);
}

// Round 4
// 1096.814 us; speedup vs baseline: 2.3821x; 2.3821x over previous
//
#include <hip/hip_runtime.h>

typedef unsigned short u16;
typedef __attribute__((ext_vector_type(8))) short v8s;
typedef __attribute__((ext_vector_type(4))) float v4f;

#define S_LEN 2048
#define HID   2048
#define NH    32
#define NKV   8
#define HD    64
#define DVV   128
#define LAMBDA_INIT  0.7455692280263525f
#define ONE_MINUS_LI 0.2544307719736475f

__device__ __forceinline__ u16 f2b(float f){
  union { float f; unsigned int i; } v; v.f = f;
  unsigned int x = v.i;
  unsigned int r = (x + 0x7fffu + ((x >> 16) & 1u)) >> 16;
  return (u16)r;
}

// C[m][n] = sum_k A[m*K+k] * B[n*K+k]   (A,B fp32; C fp32)
__global__ __launch_bounds__(256) void gemm_nt(const float* __restrict__ A, const float* __restrict__ B,
                                               float* __restrict__ C, int M, int N, int K)
{
  __shared__ __attribute__((aligned(16))) float As[16][68];
  __shared__ __attribute__((aligned(16))) float Bs[16][68];
  const int t  = threadIdx.x;
  const int m0 = blockIdx.y * 64, n0 = blockIdx.x * 64;
  const int lr = t >> 2;
  const int lq = (t & 3) * 4;
  const int tm = (t >> 4) * 4;
  const int tn = (t & 15) * 4;
  float acc[4][4] = {{0.f}};
  const float* Aptr = A + (size_t)(m0 + lr) * K + lq;
  const float* Bptr = B + (size_t)(n0 + lr) * K + lq;
  for (int k0 = 0; k0 < K; k0 += 16){
    float4 av = *(const float4*)(Aptr + k0);
    float4 bv = *(const float4*)(Bptr + k0);
    __syncthreads();
    As[lq+0][lr] = av.x; As[lq+1][lr] = av.y;
    As[lq+2][lr] = av.z; As[lq+3][lr] = av.w;
    Bs[lq+0][lr] = bv.x; Bs[lq+1][lr] = bv.y;
    Bs[lq+2][lr] = bv.z; Bs[lq+3][lr] = bv.w;
    __syncthreads();
#pragma unroll
    for (int kk = 0; kk < 16; kk++){
      float a0 = As[kk][tm+0], a1 = As[kk][tm+1], a2 = As[kk][tm+2], a3 = As[kk][tm+3];
      float b0 = Bs[kk][tn+0], b1 = Bs[kk][tn+1], b2 = Bs[kk][tn+2], b3 = Bs[kk][tn+3];
      acc[0][0] += a0*b0; acc[0][1] += a0*b1; acc[0][2] += a0*b2; acc[0][3] += a0*b3;
      acc[1][0] += a1*b0; acc[1][1] += a1*b1; acc[1][2] += a1*b2; acc[1][3] += a1*b3;
      acc[2][0] += a2*b0; acc[2][1] += a2*b1; acc[2][2] += a2*b2; acc[2][3] += a2*b3;
      acc[3][0] += a3*b0; acc[3][1] += a3*b1; acc[3][2] += a3*b2; acc[3][3] += a3*b3;
    }
  }
#pragma unroll
  for (int i = 0; i < 4; i++)
#pragma unroll
    for (int j = 0; j < 4; j++)
      C[(size_t)(m0+tm+i)*N + (n0+tn+j)] = acc[i][j];
}

// rope + cast + transpose to (nh, S, 64) bf16
__global__ __launch_bounds__(256) void rope_pack(const float* __restrict__ X,
    const float* __restrict__ cosb, const float* __restrict__ sinb,
    u16* __restrict__ Y, int nh)
{
  int idx = blockIdx.x * 256 + threadIdx.x;   // (s, h, d<32)
  int d = idx & 31;
  int h = (idx >> 5) & (nh - 1);
  int s = idx / (32 * nh);
  float c1 = cosb[s * HD + d],      s1 = sinb[s * HD + d];
  float c2 = cosb[s * HD + d + 32], s2 = sinb[s * HD + d + 32];
  size_t src = (size_t)s * ((size_t)nh * HD) + (size_t)h * HD + d;
  float x1 = X[src], x2 = X[src + 32];
  size_t dst = ((size_t)h * S_LEN + s) * HD + d;
  Y[dst]      = f2b(x1 * c1 - x2 * s1);
  Y[dst + 32] = f2b(x2 * c2 + x1 * s2);
}

// Vb fp32 (S, 8*64) -> Vt bf16 (8, 64, S)   (transposed for PV B-fragments)
__global__ __launch_bounds__(256) void vtrans(const float* __restrict__ Vb, u16* __restrict__ Vt)
{
  __shared__ u16 T[64][72];
  const int b = blockIdx.x;
  const int h = b >> 5;
  const int s0 = (b & 31) * 64;
  const int t = threadIdx.x;
#pragma unroll
  for (int i = 0; i < 4; i++){
    int u = t + i * 256;            // 64 rows(s) x 16 float4 chunks
    int r = u >> 4, c4 = (u & 15) * 4;
    float4 v = *(const float4*)&Vb[(size_t)(s0 + r) * (NKV*HD) + h * HD + c4];
    T[c4+0][r] = f2b(v.x); T[c4+1][r] = f2b(v.y);
    T[c4+2][r] = f2b(v.z); T[c4+3][r] = f2b(v.w);
  }
  __syncthreads();
#pragma unroll
  for (int i = 0; i < 2; i++){
    int u = t + i * 256;            // 64 rows(d) x 8 ushort8 chunks
    int d = u >> 3, ch = (u & 7) * 8;
    *(uint4*)&Vt[((size_t)h * HD + d) * S_LEN + s0 + ch] = *(const uint4*)&T[d][ch];
  }
}

// MFMA flash attention: Q (NH,S,64) K (NKV,S,64) Vt (NKV,64,S) all bf16 -> Att (NH,S,128) fp32
__global__ __launch_bounds__(256) void attn_mfma(const u16* __restrict__ Qbf,
                                                 const u16* __restrict__ Kbf,
                                                 const u16* __restrict__ Vt,
                                                 float* __restrict__ Att)
{
  __shared__ u16 Qs[64][72];
  __shared__ u16 Ks[64][72];
  __shared__ u16 Vs[128][72];
  __shared__ u16 Pb[64][72];

  const int h   = blockIdx.y;
  const int q0  = blockIdx.x * 64;
  const int kvh = h >> 2;
  const int c   = (h & 15) >> 2;
  const int t   = threadIdx.x;
  const int w   = t >> 6;          // wave 0..3 -> q rows 16w..16w+15
  const int lane= t & 63;
  const int mm  = lane & 15;
  const int g   = lane >> 4;       // 0..3
  const int g8  = g * 8;

  // stage Q tile (64x64 bf16)
#pragma unroll
  for (int i = 0; i < 2; i++){
    int u = t + i * 256;
    int r = u >> 3, ch = (u & 7) * 8;
    *(uint4*)&Qs[r][ch] = *(const uint4*)&Qbf[((size_t)h * S_LEN + q0 + r) * HD + ch];
  }
  __syncthreads();
  v8s qa0 = *(const v8s*)&Qs[w*16 + mm][g8];
  v8s qa1 = *(const v8s*)&Qs[w*16 + mm][32 + g8];

  v4f Sacc[4], Oacc[8];
#pragma unroll
  for (int n = 0; n < 8; n++) Oacc[n] = (v4f){0.f,0.f,0.f,0.f};
  float m_i[4] = {-1e30f,-1e30f,-1e30f,-1e30f};
  float l_i[4] = {0.f,0.f,0.f,0.f};

  for (int k0 = 0; k0 <= q0; k0 += 64){
    __syncthreads();
    // stage K tile 64x64
#pragma unroll
    for (int i = 0; i < 2; i++){
      int u = t + i * 256;
      int r = u >> 3, ch = (u & 7) * 8;
      *(uint4*)&Ks[r][ch] = *(const uint4*)&Kbf[((size_t)kvh * S_LEN + k0 + r) * HD + ch];
    }
    // stage V tile 128 dims x 64 kpos (transposed source)
#pragma unroll
    for (int i = 0; i < 4; i++){
      int u = t + i * 256;
      int d = u >> 3, ch = (u & 7) * 8;
      int head = c + ((d >> 6) << 2);
      int sd = d & 63;
      *(uint4*)&Vs[d][ch] = *(const uint4*)&Vt[((size_t)head * HD + sd) * S_LEN + k0 + ch];
    }
    __syncthreads();

    // QK^T: 4 col tiles x 2 k-chunks
#pragma unroll
    for (int n = 0; n < 4; n++){
      v8s kb0 = *(const v8s*)&Ks[n*16 + mm][g8];
      v8s kb1 = *(const v8s*)&Ks[n*16 + mm][32 + g8];
      v4f z = (v4f){0.f,0.f,0.f,0.f};
      z = __builtin_amdgcn_mfma_f32_16x16x32_bf16(qa0, kb0, z, 0, 0, 0);
      z = __builtin_amdgcn_mfma_f32_16x16x32_bf16(qa1, kb1, z, 0, 0, 0);
      Sacc[n] = z;
    }

    // mask + scale; row of reg r = q0 + 16w + 4g + r; col of tile n = k0 + 16n + mm
    const int diag = (k0 == q0);
#pragma unroll
    for (int n = 0; n < 4; n++)
#pragma unroll
      for (int r = 0; r < 4; r++){
        bool valid = !diag || (n*16 + mm <= w*16 + g*4 + r);
        Sacc[n][r] = valid ? Sacc[n][r] * 0.125f : -1e30f;
      }

    // row max over 4 tiles then 16-lane butterfly
    float mx[4];
#pragma unroll
    for (int r = 0; r < 4; r++)
      mx[r] = fmaxf(fmaxf(Sacc[0][r], Sacc[1][r]), fmaxf(Sacc[2][r], Sacc[3][r]));
#pragma unroll
    for (int off = 1; off < 16; off <<= 1)
#pragma unroll
      for (int r = 0; r < 4; r++)
        mx[r] = fmaxf(mx[r], __shfl_xor(mx[r], off));

    float alpha[4];
#pragma unroll
    for (int r = 0; r < 4; r++){
      float mnew = fmaxf(m_i[r], mx[r]);
      alpha[r] = __expf(m_i[r] - mnew);
      m_i[r] = mnew;
    }
    // exp, row sum, write P bf16 (each wave writes only its own 16 rows)
    float sm[4] = {0.f,0.f,0.f,0.f};
#pragma unroll
    for (int n = 0; n < 4; n++)
#pragma unroll
      for (int r = 0; r < 4; r++){
        float p = __expf(Sacc[n][r] - m_i[r]);
        sm[r] += p;
        Pb[w*16 + g*4 + r][n*16 + mm] = f2b(p);
      }
#pragma unroll
    for (int off = 1; off < 16; off <<= 1)
#pragma unroll
      for (int r = 0; r < 4; r++)
        sm[r] += __shfl_xor(sm[r], off);
#pragma unroll
    for (int r = 0; r < 4; r++) l_i[r] = alpha[r] * l_i[r] + sm[r];

    // rescale O
#pragma unroll
    for (int n = 0; n < 8; n++)
#pragma unroll
      for (int r = 0; r < 4; r++)
        Oacc[n][r] *= alpha[r];

    // PV: P A-frags (own rows -> same-wave DS ordering, no barrier needed)
    v8s pa0 = *(const v8s*)&Pb[w*16 + mm][g8];
    v8s pa1 = *(const v8s*)&Pb[w*16 + mm][32 + g8];
#pragma unroll
    for (int n = 0; n < 8; n++){
      v8s vb0 = *(const v8s*)&Vs[n*16 + mm][g8];
      v8s vb1 = *(const v8s*)&Vs[n*16 + mm][32 + g8];
      Oacc[n] = __builtin_amdgcn_mfma_f32_16x16x32_bf16(pa0, vb0, Oacc[n], 0, 0, 0);
      Oacc[n] = __builtin_amdgcn_mfma_f32_16x16x32_bf16(pa1, vb1, Oacc[n], 0, 0, 0);
    }
  }

  // epilogue
  float inv_l[4];
#pragma unroll
  for (int r = 0; r < 4; r++) inv_l[r] = 1.0f / l_i[r];
#pragma unroll
  for (int n = 0; n < 8; n++)
#pragma unroll
    for (int r = 0; r < 4; r++){
      int srow = q0 + w*16 + g*4 + r;
      Att[((size_t)h * S_LEN + srow) * DVV + n*16 + mm] = Oacc[n][r] * inv_l[r];
    }
}

// a = att[h] - lam*att[h+16]; RMS-norm over 128; scale; write fp32 ctx (S, 16*128)
__global__ __launch_bounds__(128) void diff_rms(const float* __restrict__ Att,
    const float* __restrict__ lq1, const float* __restrict__ lk1,
    const float* __restrict__ lq2, const float* __restrict__ lk2,
    float* __restrict__ Ctx)
{
  __shared__ float lamS;
  __shared__ float red[2];
  const int blk = blockIdx.x;
  const int h = blk & 15;
  const int s = blk >> 4;
  const int d = threadIdx.x;   // 0..127
  if (d < 64){
    float p1 = lq1[d] * lk1[d];
    float p2 = lq2[d] * lk2[d];
#pragma unroll
    for (int off = 32; off; off >>= 1){
      p1 += __shfl_down(p1, off);
      p2 += __shfl_down(p2, off);
    }
    if (d == 0) lamS = __expf(p1) - __expf(p2) + LAMBDA_INIT;
  }
  __syncthreads();
  const float lam = lamS;
  float a = Att[((size_t)h * S_LEN + s) * DVV + d]
          - lam * Att[((size_t)(h+16) * S_LEN + s) * DVV + d];
  float ss = a * a;
#pragma unroll
  for (int off = 32; off; off >>= 1) ss += __shfl_down(ss, off);
  if ((d & 63) == 0) red[d >> 6] = ss;
  __syncthreads();
  float tot = red[0] + red[1];
  float rinv = rsqrtf(tot * (1.0f/128.0f) + 1e-6f);
  Ctx[(size_t)s * HID + h * DVV + d] = ONE_MINUS_LI * a * rinv;
}

extern "C" void kernel_launch(void* const* d_in, const int* in_sizes, int n_in,
                              void* d_out, int out_size, void* d_ws, size_t ws_size,
                              hipStream_t stream)
{
  (void)in_sizes; (void)n_in; (void)out_size; (void)ws_size;
  const float* hs   = (const float*)d_in[0];
  const float* cosb = (const float*)d_in[1];
  const float* sinb = (const float*)d_in[2];
  const float* Wq   = (const float*)d_in[3];
  const float* Wk   = (const float*)d_in[4];
  const float* Wv   = (const float*)d_in[5];
  const float* Wo   = (const float*)d_in[6];
  const float* lq1  = (const float*)d_in[7];
  const float* lk1  = (const float*)d_in[8];
  const float* lq2  = (const float*)d_in[9];
  const float* lk2  = (const float*)d_in[10];

  char* ws = (char*)d_ws;
  float* Qb  = (float*)(ws);                     // 16 MB fp32 (S,2048)
  float* Kb  = (float*)(ws + (16u << 20));       // 4 MB fp32 (S,512)
  float* Vb  = (float*)(ws + (20u << 20));       // 4 MB fp32 (S,512)
  float* Att = (float*)(ws + (24u << 20));       // 32 MB fp32 (32,S,128)
  u16*   Qbf = (u16*)(ws + (16u << 20));         // 8 MB bf16 (32,S,64) — overlays Kb/Vb AFTER they are consumed
  u16*   Kbf = (u16*)(ws + (56u << 20));         // 2 MB bf16 (8,S,64)
  u16*   Vt  = (u16*)(ws + (58u << 20));         // 2 MB bf16 (8,64,S)
  float* Ctx = (float*)(ws);                     // 16 MB, overlays Qb

  gemm_nt<<<dim3(32, 32), 256, 0, stream>>>(hs, Wq, Qb, S_LEN, 2048, HID);
  gemm_nt<<<dim3(8, 32), 256, 0, stream>>>(hs, Wk, Kb, S_LEN, 512, HID);
  gemm_nt<<<dim3(8, 32), 256, 0, stream>>>(hs, Wv, Vb, S_LEN, 512, HID);
  // consume Kb, Vb first; then Qb -> Qbf may overwrite Kb/Vb region
  rope_pack<<<2048, 256, 0, stream>>>(Kb, cosb, sinb, Kbf, NKV);
  vtrans<<<NKV * (S_LEN/64), 256, 0, stream>>>(Vb, Vt);
  rope_pack<<<8192, 256, 0, stream>>>(Qb, cosb, sinb, Qbf, NH);
  attn_mfma<<<dim3(S_LEN/64, NH), 256, 0, stream>>>(Qbf, Kbf, Vt, Att);
  diff_rms<<<16 * S_LEN, 128, 0, stream>>>(Att, lq1, lk1, lq2, lk2, Ctx);
  gemm_nt<<<dim3(32, 32), 256, 0, stream>>>(Ctx, Wo, (float*)d_out, S_LEN, 2048, HID);
}

// Round 5
// 480.451 us; speedup vs baseline: 5.4380x; 2.2829x over previous
//
#include <hip/hip_runtime.h>

typedef unsigned short u16;
typedef __attribute__((ext_vector_type(8))) short v8s;
typedef __attribute__((ext_vector_type(4))) float v4f;

#define S_LEN 2048
#define HID   2048
#define NH    32
#define NKV   8
#define HD    64
#define DVV   128
#define LAMBDA_INIT  0.7455692280263525f
#define ONE_MINUS_LI 0.2544307719736475f

__device__ __forceinline__ u16 f2b(float f){
  union { float f; unsigned int i; } v; v.f = f;
  unsigned int x = v.i;
  unsigned int r = (x + 0x7fffu + ((x >> 16) & 1u)) >> 16;
  return (u16)r;
}

__device__ __forceinline__ void gld16(const u16* g, u16* l){
  __builtin_amdgcn_global_load_lds(
      (const __attribute__((address_space(1))) unsigned int*)g,
      (__attribute__((address_space(3))) unsigned int*)l, 16, 0, 0);
}

// fp32 -> bf16 cast, 8 elems/thread; n multiple of 2048
__global__ __launch_bounds__(256) void cast_bf16(const float* __restrict__ X, u16* __restrict__ Y, int n)
{
  int i = (blockIdx.x * 256 + threadIdx.x) * 8;
  if (i >= n) return;
  float4 a = *(const float4*)(X + i);
  float4 b = *(const float4*)(X + i + 4);
  u16 o[8] = {f2b(a.x), f2b(a.y), f2b(a.z), f2b(a.w), f2b(b.x), f2b(b.y), f2b(b.z), f2b(b.w)};
  *(uint4*)(Y + i) = *(const uint4*)o;
}

// C[m][n] = sum_k A[m*K+k]*B[n*K+k]; A,B bf16; C fp32. 128x128 tile, BK=64,
// global_load_lds staging with XOR chunk swizzle (row&7) to kill bank conflicts.
__global__ __launch_bounds__(256) void gemm_bf16(const u16* __restrict__ A, const u16* __restrict__ B,
                                                 float* __restrict__ C, int M, int N, int K)
{
  __shared__ __attribute__((aligned(16))) u16 As[128*64];
  __shared__ __attribute__((aligned(16))) u16 Bs[128*64];
  const int t    = threadIdx.x;
  const int w    = t >> 6, lane = t & 63;
  const int mm   = lane & 15, g = lane >> 4;
  const int wr   = w >> 1, wc = w & 1;
  const int m0   = blockIdx.y * 128, n0 = blockIdx.x * 128;
  const int srow = w*32 + (lane >> 3);   // +i*8 ; 8 lanes per 128B row
  const int sch  = lane & 7;             // 16B chunk slot within row

  v4f acc[4][4];
#pragma unroll
  for (int i = 0; i < 4; i++)
#pragma unroll
    for (int j = 0; j < 4; j++) acc[i][j] = (v4f){0.f,0.f,0.f,0.f};

  for (int k0 = 0; k0 < K; k0 += 64){
    __syncthreads();
#pragma unroll
    for (int i = 0; i < 4; i++){
      int r  = srow + i*8;
      int ce = ((sch ^ (r & 7)) * 8);    // global chunk fetched into slot sch
      gld16(A + (size_t)(m0 + r) * K + k0 + ce, &As[w*2048 + i*512]);
      gld16(B + (size_t)(n0 + r) * K + k0 + ce, &Bs[w*2048 + i*512]);
    }
    __syncthreads();
#pragma unroll
    for (int kc = 0; kc < 2; kc++){
      v8s af[4], bf[4];
#pragma unroll
      for (int i = 0; i < 4; i++){
        int r = wr*64 + i*16 + mm;
        af[i] = *(const v8s*)&As[r*64 + (((kc*4 + g) ^ (r & 7)) * 8)];
      }
#pragma unroll
      for (int j = 0; j < 4; j++){
        int r = wc*64 + j*16 + mm;
        bf[j] = *(const v8s*)&Bs[r*64 + (((kc*4 + g) ^ (r & 7)) * 8)];
      }
#pragma unroll
      for (int i = 0; i < 4; i++)
#pragma unroll
        for (int j = 0; j < 4; j++)
          acc[i][j] = __builtin_amdgcn_mfma_f32_16x16x32_bf16(af[i], bf[j], acc[i][j], 0, 0, 0);
    }
  }
#pragma unroll
  for (int i = 0; i < 4; i++)
#pragma unroll
    for (int j = 0; j < 4; j++)
#pragma unroll
      for (int r = 0; r < 4; r++)
        C[(size_t)(m0 + wr*64 + i*16 + g*4 + r) * N + n0 + wc*64 + j*16 + mm] = acc[i][j][r];
}

// rope + cast + transpose to (nh, S, 64) bf16; X rows have stride `stride`
__global__ __launch_bounds__(256) void rope_pack(const float* __restrict__ X, int stride,
    const float* __restrict__ cosb, const float* __restrict__ sinb,
    u16* __restrict__ Y, int nh)
{
  int idx = blockIdx.x * 256 + threadIdx.x;   // (s, h, d<32)
  int d = idx & 31;
  int h = (idx >> 5) & (nh - 1);
  int s = idx / (32 * nh);
  float c1 = cosb[s * HD + d],      s1 = sinb[s * HD + d];
  float c2 = cosb[s * HD + d + 32], s2 = sinb[s * HD + d + 32];
  size_t src = (size_t)s * stride + (size_t)h * HD + d;
  float x1 = X[src], x2 = X[src + 32];
  size_t dst = ((size_t)h * S_LEN + s) * HD + d;
  Y[dst]      = f2b(x1 * c1 - x2 * s1);
  Y[dst + 32] = f2b(x2 * c2 + x1 * s2);
}

// V fp32 rows (stride `stride`, 8 heads at col h*64) -> Vt bf16 (8, 64, S)
__global__ __launch_bounds__(256) void vtrans(const float* __restrict__ Vb, int stride, u16* __restrict__ Vt)
{
  __shared__ u16 T[64][72];
  const int b = blockIdx.x;
  const int h = b >> 5;
  const int s0 = (b & 31) * 64;
  const int t = threadIdx.x;
#pragma unroll
  for (int i = 0; i < 4; i++){
    int u = t + i * 256;
    int r = u >> 4, c4 = (u & 15) * 4;
    float4 v = *(const float4*)&Vb[(size_t)(s0 + r) * stride + h * HD + c4];
    T[c4+0][r] = f2b(v.x); T[c4+1][r] = f2b(v.y);
    T[c4+2][r] = f2b(v.z); T[c4+3][r] = f2b(v.w);
  }
  __syncthreads();
#pragma unroll
  for (int i = 0; i < 2; i++){
    int u = t + i * 256;
    int d = u >> 3, ch = (u & 7) * 8;
    *(uint4*)&Vt[((size_t)h * HD + d) * S_LEN + s0 + ch] = *(const uint4*)&T[d][ch];
  }
}

// MFMA flash attention: Q (NH,S,64) K (NKV,S,64) Vt (NKV,64,S) all bf16 -> Att (NH,S,128) fp32
__global__ __launch_bounds__(256) void attn_mfma(const u16* __restrict__ Qbf,
                                                 const u16* __restrict__ Kbf,
                                                 const u16* __restrict__ Vt,
                                                 float* __restrict__ Att)
{
  __shared__ u16 Qs[64][72];
  __shared__ u16 Ks[64][72];
  __shared__ u16 Vs[128][72];
  __shared__ u16 Pb[64][72];

  const int h   = blockIdx.y;
  const int q0  = blockIdx.x * 64;
  const int kvh = h >> 2;
  const int c   = (h & 15) >> 2;
  const int t   = threadIdx.x;
  const int w   = t >> 6;
  const int lane= t & 63;
  const int mm  = lane & 15;
  const int g   = lane >> 4;
  const int g8  = g * 8;

#pragma unroll
  for (int i = 0; i < 2; i++){
    int u = t + i * 256;
    int r = u >> 3, ch = (u & 7) * 8;
    *(uint4*)&Qs[r][ch] = *(const uint4*)&Qbf[((size_t)h * S_LEN + q0 + r) * HD + ch];
  }
  __syncthreads();
  v8s qa0 = *(const v8s*)&Qs[w*16 + mm][g8];
  v8s qa1 = *(const v8s*)&Qs[w*16 + mm][32 + g8];

  v4f Sacc[4], Oacc[8];
#pragma unroll
  for (int n = 0; n < 8; n++) Oacc[n] = (v4f){0.f,0.f,0.f,0.f};
  float m_i[4] = {-1e30f,-1e30f,-1e30f,-1e30f};
  float l_i[4] = {0.f,0.f,0.f,0.f};

  for (int k0 = 0; k0 <= q0; k0 += 64){
    __syncthreads();
#pragma unroll
    for (int i = 0; i < 2; i++){
      int u = t + i * 256;
      int r = u >> 3, ch = (u & 7) * 8;
      *(uint4*)&Ks[r][ch] = *(const uint4*)&Kbf[((size_t)kvh * S_LEN + k0 + r) * HD + ch];
    }
#pragma unroll
    for (int i = 0; i < 4; i++){
      int u = t + i * 256;
      int d = u >> 3, ch = (u & 7) * 8;
      int head = c + ((d >> 6) << 2);
      int sd = d & 63;
      *(uint4*)&Vs[d][ch] = *(const uint4*)&Vt[((size_t)head * HD + sd) * S_LEN + k0 + ch];
    }
    __syncthreads();

#pragma unroll
    for (int n = 0; n < 4; n++){
      v8s kb0 = *(const v8s*)&Ks[n*16 + mm][g8];
      v8s kb1 = *(const v8s*)&Ks[n*16 + mm][32 + g8];
      v4f z = (v4f){0.f,0.f,0.f,0.f};
      z = __builtin_amdgcn_mfma_f32_16x16x32_bf16(qa0, kb0, z, 0, 0, 0);
      z = __builtin_amdgcn_mfma_f32_16x16x32_bf16(qa1, kb1, z, 0, 0, 0);
      Sacc[n] = z;
    }

    const int diag = (k0 == q0);
#pragma unroll
    for (int n = 0; n < 4; n++)
#pragma unroll
      for (int r = 0; r < 4; r++){
        bool valid = !diag || (n*16 + mm <= w*16 + g*4 + r);
        Sacc[n][r] = valid ? Sacc[n][r] * 0.125f : -1e30f;
      }

    float mx[4];
#pragma unroll
    for (int r = 0; r < 4; r++)
      mx[r] = fmaxf(fmaxf(Sacc[0][r], Sacc[1][r]), fmaxf(Sacc[2][r], Sacc[3][r]));
#pragma unroll
    for (int off = 1; off < 16; off <<= 1)
#pragma unroll
      for (int r = 0; r < 4; r++)
        mx[r] = fmaxf(mx[r], __shfl_xor(mx[r], off));

    float alpha[4];
#pragma unroll
    for (int r = 0; r < 4; r++){
      float mnew = fmaxf(m_i[r], mx[r]);
      alpha[r] = __expf(m_i[r] - mnew);
      m_i[r] = mnew;
    }
    float sm[4] = {0.f,0.f,0.f,0.f};
#pragma unroll
    for (int n = 0; n < 4; n++)
#pragma unroll
      for (int r = 0; r < 4; r++){
        float p = __expf(Sacc[n][r] - m_i[r]);
        sm[r] += p;
        Pb[w*16 + g*4 + r][n*16 + mm] = f2b(p);
      }
#pragma unroll
    for (int off = 1; off < 16; off <<= 1)
#pragma unroll
      for (int r = 0; r < 4; r++)
        sm[r] += __shfl_xor(sm[r], off);
#pragma unroll
    for (int r = 0; r < 4; r++) l_i[r] = alpha[r] * l_i[r] + sm[r];

#pragma unroll
    for (int n = 0; n < 8; n++)
#pragma unroll
      for (int r = 0; r < 4; r++)
        Oacc[n][r] *= alpha[r];

    v8s pa0 = *(const v8s*)&Pb[w*16 + mm][g8];
    v8s pa1 = *(const v8s*)&Pb[w*16 + mm][32 + g8];
#pragma unroll
    for (int n = 0; n < 8; n++){
      v8s vb0 = *(const v8s*)&Vs[n*16 + mm][g8];
      v8s vb1 = *(const v8s*)&Vs[n*16 + mm][32 + g8];
      Oacc[n] = __builtin_amdgcn_mfma_f32_16x16x32_bf16(pa0, vb0, Oacc[n], 0, 0, 0);
      Oacc[n] = __builtin_amdgcn_mfma_f32_16x16x32_bf16(pa1, vb1, Oacc[n], 0, 0, 0);
    }
  }

  float inv_l[4];
#pragma unroll
  for (int r = 0; r < 4; r++) inv_l[r] = 1.0f / l_i[r];
#pragma unroll
  for (int n = 0; n < 8; n++)
#pragma unroll
    for (int r = 0; r < 4; r++){
      int srow = q0 + w*16 + g*4 + r;
      Att[((size_t)h * S_LEN + srow) * DVV + n*16 + mm] = Oacc[n][r] * inv_l[r];
    }
}

// a = att[h] - lam*att[h+16]; RMS over 128; scale; write bf16 Ctx (S, 16*128)
__global__ __launch_bounds__(128) void diff_rms(const float* __restrict__ Att,
    const float* __restrict__ lq1, const float* __restrict__ lk1,
    const float* __restrict__ lq2, const float* __restrict__ lk2,
    u16* __restrict__ Ctx)
{
  __shared__ float lamS;
  __shared__ float red[2];
  const int blk = blockIdx.x;
  const int h = blk & 15;
  const int s = blk >> 4;
  const int d = threadIdx.x;
  if (d < 64){
    float p1 = lq1[d] * lk1[d];
    float p2 = lq2[d] * lk2[d];
#pragma unroll
    for (int off = 32; off; off >>= 1){
      p1 += __shfl_down(p1, off);
      p2 += __shfl_down(p2, off);
    }
    if (d == 0) lamS = __expf(p1) - __expf(p2) + LAMBDA_INIT;
  }
  __syncthreads();
  const float lam = lamS;
  float a = Att[((size_t)h * S_LEN + s) * DVV + d]
          - lam * Att[((size_t)(h+16) * S_LEN + s) * DVV + d];
  float ss = a * a;
#pragma unroll
  for (int off = 32; off; off >>= 1) ss += __shfl_down(ss, off);
  if ((d & 63) == 0) red[d >> 6] = ss;
  __syncthreads();
  float tot = red[0] + red[1];
  float rinv = rsqrtf(tot * (1.0f/128.0f) + 1e-6f);
  Ctx[(size_t)s * HID + h * DVV + d] = f2b(ONE_MINUS_LI * a * rinv);
}

extern "C" void kernel_launch(void* const* d_in, const int* in_sizes, int n_in,
                              void* d_out, int out_size, void* d_ws, size_t ws_size,
                              hipStream_t stream)
{
  (void)in_sizes; (void)n_in; (void)out_size; (void)ws_size;
  const float* hs   = (const float*)d_in[0];
  const float* cosb = (const float*)d_in[1];
  const float* sinb = (const float*)d_in[2];
  const float* Wq   = (const float*)d_in[3];
  const float* Wk   = (const float*)d_in[4];
  const float* Wv   = (const float*)d_in[5];
  const float* Wo   = (const float*)d_in[6];
  const float* lq1  = (const float*)d_in[7];
  const float* lk1  = (const float*)d_in[8];
  const float* lq2  = (const float*)d_in[9];
  const float* lk2  = (const float*)d_in[10];

  char* ws = (char*)d_ws;
  float* Qb  = (float*)(ws);                     // 0-16 MB fp32 (S,2048); later Ctx bf16 0-8
  float* KVb = (float*)(ws + (16u << 20));       // 16-24 MB fp32 (S,1024) K|V; later Qbf, later Wob
  float* Att = (float*)(ws + (24u << 20));       // 24-56 MB fp32 (32,S,128)
  u16*   hsb = (u16*)(ws + (24u << 20));         // 24-32 MB bf16 (dead before Att written)
  u16*   Wsb = (u16*)(ws + (32u << 20));         // 32-40 MB bf16 weight scratch (dead before Att)
  u16*   Kbf = (u16*)(ws + (56u << 20));         // 56-58 MB bf16 (8,S,64)
  u16*   Vt  = (u16*)(ws + (58u << 20));         // 58-60 MB bf16 (8,64,S)
  u16*   Qbf = (u16*)(ws + (16u << 20));         // overlays KVb (dead after Kbf/Vt built)
  u16*   Wob = (u16*)(ws + (16u << 20));         // overlays Qbf (dead after attn)
  u16*   Ctx = (u16*)(ws);                       // overlays Qb

  cast_bf16<<<2048, 256, 0, stream>>>(hs, hsb, HID * S_LEN);
  cast_bf16<<<2048, 256, 0, stream>>>(Wq, Wsb, 2048 * 2048);
  gemm_bf16<<<dim3(16, 16), 256, 0, stream>>>(hsb, Wsb, Qb, S_LEN, 2048, HID);
  cast_bf16<<<512, 256, 0, stream>>>(Wk, Wsb, 512 * 2048);
  cast_bf16<<<512, 256, 0, stream>>>(Wv, Wsb + 512 * 2048, 512 * 2048);
  gemm_bf16<<<dim3(8, 16), 256, 0, stream>>>(hsb, Wsb, KVb, S_LEN, 1024, HID);
  rope_pack<<<2048, 256, 0, stream>>>(KVb, 1024, cosb, sinb, Kbf, NKV);
  vtrans<<<NKV * (S_LEN/64), 256, 0, stream>>>(KVb + 512, 1024, Vt);
  rope_pack<<<8192, 256, 0, stream>>>(Qb, 2048, cosb, sinb, Qbf, NH);
  attn_mfma<<<dim3(S_LEN/64, NH), 256, 0, stream>>>(Qbf, Kbf, Vt, Att);
  cast_bf16<<<2048, 256, 0, stream>>>(Wo, Wob, 2048 * 2048);
  diff_rms<<<16 * S_LEN, 128, 0, stream>>>(Att, lq1, lk1, lq2, lk2, Ctx);
  gemm_bf16<<<dim3(16, 16), 256, 0, stream>>>(Ctx, Wob, (float*)d_out, S_LEN, 2048, HID);
}

// Round 6
// 455.614 us; speedup vs baseline: 5.7345x; 1.0545x over previous
//
#include <hip/hip_runtime.h>

typedef unsigned short u16;
typedef __attribute__((ext_vector_type(8))) short v8s;
typedef __attribute__((ext_vector_type(4))) float v4f;

#define S_LEN 2048
#define HID   2048
#define NH    32
#define NKV   8
#define HD    64
#define DVV   128
#define LAMBDA_INIT  0.7455692280263525f
#define ONE_MINUS_LI 0.2544307719736475f

__device__ __forceinline__ u16 f2b(float f){
  union { float f; unsigned int i; } v; v.f = f;
  unsigned int x = v.i;
  unsigned int r = (x + 0x7fffu + ((x >> 16) & 1u)) >> 16;
  return (u16)r;
}

__device__ __forceinline__ void gld16(const u16* g, u16* l){
  __builtin_amdgcn_global_load_lds(
      (const __attribute__((address_space(1))) unsigned int*)g,
      (__attribute__((address_space(3))) unsigned int*)l, 16, 0, 0);
}

// fp32 -> bf16 cast, 8 elems/thread
__global__ __launch_bounds__(256) void cast_bf16(const float* __restrict__ X, u16* __restrict__ Y, int n)
{
  int i = (blockIdx.x * 256 + threadIdx.x) * 8;
  if (i >= n) return;
  float4 a = *(const float4*)(X + i);
  float4 b = *(const float4*)(X + i + 4);
  u16 o[8] = {f2b(a.x), f2b(a.y), f2b(a.z), f2b(a.w), f2b(b.x), f2b(b.y), f2b(b.z), f2b(b.w)};
  *(uint4*)(Y + i) = *(const uint4*)o;
}

// C[m][n] = sum_k A[m*K+k]*B[n*K+k]; A,B bf16; C fp32. 128x128 tile, BK=64,
// global_load_lds staging with XOR chunk swizzle (row&7).
__global__ __launch_bounds__(256) void gemm_bf16(const u16* __restrict__ A, const u16* __restrict__ B,
                                                 float* __restrict__ C, int M, int N, int K)
{
  __shared__ __attribute__((aligned(16))) u16 As[128*64];
  __shared__ __attribute__((aligned(16))) u16 Bs[128*64];
  const int t    = threadIdx.x;
  const int w    = t >> 6, lane = t & 63;
  const int mm   = lane & 15, g = lane >> 4;
  const int wr   = w >> 1, wc = w & 1;
  const int m0   = blockIdx.y * 128, n0 = blockIdx.x * 128;
  const int srow = w*32 + (lane >> 3);
  const int sch  = lane & 7;

  v4f acc[4][4];
#pragma unroll
  for (int i = 0; i < 4; i++)
#pragma unroll
    for (int j = 0; j < 4; j++) acc[i][j] = (v4f){0.f,0.f,0.f,0.f};

  for (int k0 = 0; k0 < K; k0 += 64){
    __syncthreads();
#pragma unroll
    for (int i = 0; i < 4; i++){
      int r  = srow + i*8;
      int ce = ((sch ^ (r & 7)) * 8);
      gld16(A + (size_t)(m0 + r) * K + k0 + ce, &As[w*2048 + i*512]);
      gld16(B + (size_t)(n0 + r) * K + k0 + ce, &Bs[w*2048 + i*512]);
    }
    __syncthreads();
#pragma unroll
    for (int kc = 0; kc < 2; kc++){
      v8s af[4], bf[4];
#pragma unroll
      for (int i = 0; i < 4; i++){
        int r = wr*64 + i*16 + mm;
        af[i] = *(const v8s*)&As[r*64 + (((kc*4 + g) ^ (r & 7)) * 8)];
      }
#pragma unroll
      for (int j = 0; j < 4; j++){
        int r = wc*64 + j*16 + mm;
        bf[j] = *(const v8s*)&Bs[r*64 + (((kc*4 + g) ^ (r & 7)) * 8)];
      }
#pragma unroll
      for (int i = 0; i < 4; i++)
#pragma unroll
        for (int j = 0; j < 4; j++)
          acc[i][j] = __builtin_amdgcn_mfma_f32_16x16x32_bf16(af[i], bf[j], acc[i][j], 0, 0, 0);
    }
  }
#pragma unroll
  for (int i = 0; i < 4; i++)
#pragma unroll
    for (int j = 0; j < 4; j++)
#pragma unroll
      for (int r = 0; r < 4; r++)
        C[(size_t)(m0 + wr*64 + i*16 + g*4 + r) * N + n0 + wc*64 + j*16 + mm] = acc[i][j][r];
}

// rope + cast + transpose to (nh, S, 64) bf16; X rows have stride `stride`
__global__ __launch_bounds__(256) void rope_pack(const float* __restrict__ X, int stride,
    const float* __restrict__ cosb, const float* __restrict__ sinb,
    u16* __restrict__ Y, int nh)
{
  int idx = blockIdx.x * 256 + threadIdx.x;
  int d = idx & 31;
  int h = (idx >> 5) & (nh - 1);
  int s = idx / (32 * nh);
  float c1 = cosb[s * HD + d],      s1 = sinb[s * HD + d];
  float c2 = cosb[s * HD + d + 32], s2 = sinb[s * HD + d + 32];
  size_t src = (size_t)s * stride + (size_t)h * HD + d;
  float x1 = X[src], x2 = X[src + 32];
  size_t dst = ((size_t)h * S_LEN + s) * HD + d;
  Y[dst]      = f2b(x1 * c1 - x2 * s1);
  Y[dst + 32] = f2b(x2 * c2 + x1 * s2);
}

// V fp32 rows (stride, head h at col h*64) -> Vt bf16 (8, 64, S)
__global__ __launch_bounds__(256) void vtrans(const float* __restrict__ Vb, int stride, u16* __restrict__ Vt)
{
  __shared__ u16 T[64][72];
  const int b = blockIdx.x;
  const int h = b >> 5;
  const int s0 = (b & 31) * 64;
  const int t = threadIdx.x;
#pragma unroll
  for (int i = 0; i < 4; i++){
    int u = t + i * 256;
    int r = u >> 4, c4 = (u & 15) * 4;
    float4 v = *(const float4*)&Vb[(size_t)(s0 + r) * stride + h * HD + c4];
    T[c4+0][r] = f2b(v.x); T[c4+1][r] = f2b(v.y);
    T[c4+2][r] = f2b(v.z); T[c4+3][r] = f2b(v.w);
  }
  __syncthreads();
#pragma unroll
  for (int i = 0; i < 2; i++){
    int u = t + i * 256;
    int d = u >> 3, ch = (u & 7) * 8;
    *(uint4*)&Vt[((size_t)h * HD + d) * S_LEN + s0 + ch] = *(const uint4*)&T[d][ch];
  }
}

// MFMA flash attention. Q (NH,S,64) K (NKV,S,64) Vt (NKV,64,S) bf16 -> Att (NH,S,128) fp32
// P-tile aliases the Q-tile LDS (both wave-private after the pre-loop fragment reads).
// K/V register prefetch; longest-first q-block order.
__global__ __launch_bounds__(256, 4) void attn_mfma(const u16* __restrict__ Qbf,
                                                    const u16* __restrict__ Kbf,
                                                    const u16* __restrict__ Vt,
                                                    float* __restrict__ Att)
{
  __shared__ u16 QPs[64][72];     // Q tile, then P tile
  __shared__ u16 Ks[64][72];
  __shared__ u16 Vs[128][72];

  const int h   = blockIdx.y;
  const int q0  = (gridDim.x - 1 - blockIdx.x) * 64;   // longest blocks first
  const int kvh = h >> 2;
  const int c   = (h & 15) >> 2;
  const int t   = threadIdx.x;
  const int w   = t >> 6;
  const int lane= t & 63;
  const int mm  = lane & 15;
  const int g   = lane >> 4;
  const int g8  = g * 8;
  const int sr  = t >> 3;          // staging row 0..31 (+32 per i)
  const int sch = (t & 7) * 8;     // staging chunk

  // stage Q tile
#pragma unroll
  for (int i = 0; i < 2; i++)
    *(uint4*)&QPs[sr + i*32][sch] = *(const uint4*)&Qbf[((size_t)h * S_LEN + q0 + sr + i*32) * HD + sch];
  __syncthreads();
  v8s qa0 = *(const v8s*)&QPs[w*16 + mm][g8];
  v8s qa1 = *(const v8s*)&QPs[w*16 + mm][32 + g8];

  v4f Sacc[4], Oacc[8];
#pragma unroll
  for (int n = 0; n < 8; n++) Oacc[n] = (v4f){0.f,0.f,0.f,0.f};
  float m_i[4] = {-1e30f,-1e30f,-1e30f,-1e30f};
  float l_i[4] = {0.f,0.f,0.f,0.f};

  // prefetch sources
  const u16* kbase = Kbf + (size_t)kvh * S_LEN * HD + (size_t)sr * HD + sch;       // +i*32*HD, +k0*HD
  const u16* vbase0 = Vt + ((size_t)(c + (((sr    ) >> 6) << 2)) * HD + ((sr    ) & 63)) * S_LEN + sch;
  uint4 kreg[2], vreg[4];
#pragma unroll
  for (int i = 0; i < 2; i++) kreg[i] = *(const uint4*)(kbase + (size_t)i*32*HD);
#pragma unroll
  for (int i = 0; i < 4; i++){
    int d = sr + i*32;
    vreg[i] = *(const uint4*)&Vt[((size_t)(c + ((d >> 6) << 2)) * HD + (d & 63)) * S_LEN + sch];
  }
  (void)vbase0;

  for (int k0 = 0; k0 <= q0; k0 += 64){
    __syncthreads();                       // prior compute done reading Ks/Vs
#pragma unroll
    for (int i = 0; i < 2; i++) *(uint4*)&Ks[sr + i*32][sch] = kreg[i];
#pragma unroll
    for (int i = 0; i < 4; i++) *(uint4*)&Vs[sr + i*32][sch] = vreg[i];
    __syncthreads();                       // staging visible
    if (k0 + 64 <= q0){                    // prefetch next tile (drains during compute)
#pragma unroll
      for (int i = 0; i < 2; i++) kreg[i] = *(const uint4*)(kbase + (size_t)(k0+64+i*32)*HD);
#pragma unroll
      for (int i = 0; i < 4; i++){
        int d = sr + i*32;
        vreg[i] = *(const uint4*)&Vt[((size_t)(c + ((d >> 6) << 2)) * HD + (d & 63)) * S_LEN + k0 + 64 + sch];
      }
    }

#pragma unroll
    for (int n = 0; n < 4; n++){
      v8s kb0 = *(const v8s*)&Ks[n*16 + mm][g8];
      v8s kb1 = *(const v8s*)&Ks[n*16 + mm][32 + g8];
      v4f z = (v4f){0.f,0.f,0.f,0.f};
      z = __builtin_amdgcn_mfma_f32_16x16x32_bf16(qa0, kb0, z, 0, 0, 0);
      z = __builtin_amdgcn_mfma_f32_16x16x32_bf16(qa1, kb1, z, 0, 0, 0);
      Sacc[n] = z;
    }

    const int diag = (k0 == q0);
#pragma unroll
    for (int n = 0; n < 4; n++)
#pragma unroll
      for (int r = 0; r < 4; r++){
        bool valid = !diag || (n*16 + mm <= w*16 + g*4 + r);
        Sacc[n][r] = valid ? Sacc[n][r] * 0.125f : -1e30f;
      }

    float mx[4];
#pragma unroll
    for (int r = 0; r < 4; r++)
      mx[r] = fmaxf(fmaxf(Sacc[0][r], Sacc[1][r]), fmaxf(Sacc[2][r], Sacc[3][r]));
#pragma unroll
    for (int off = 1; off < 16; off <<= 1)
#pragma unroll
      for (int r = 0; r < 4; r++)
        mx[r] = fmaxf(mx[r], __shfl_xor(mx[r], off));

    float alpha[4];
#pragma unroll
    for (int r = 0; r < 4; r++){
      float mnew = fmaxf(m_i[r], mx[r]);
      alpha[r] = __expf(m_i[r] - mnew);
      m_i[r] = mnew;
    }
    float sm[4] = {0.f,0.f,0.f,0.f};
#pragma unroll
    for (int n = 0; n < 4; n++)
#pragma unroll
      for (int r = 0; r < 4; r++){
        float p = __expf(Sacc[n][r] - m_i[r]);
        sm[r] += p;
        QPs[w*16 + g*4 + r][n*16 + mm] = f2b(p);   // wave-private rows
      }
#pragma unroll
    for (int off = 1; off < 16; off <<= 1)
#pragma unroll
      for (int r = 0; r < 4; r++)
        sm[r] += __shfl_xor(sm[r], off);
#pragma unroll
    for (int r = 0; r < 4; r++) l_i[r] = alpha[r] * l_i[r] + sm[r];

#pragma unroll
    for (int n = 0; n < 8; n++)
#pragma unroll
      for (int r = 0; r < 4; r++)
        Oacc[n][r] *= alpha[r];

    v8s pa0 = *(const v8s*)&QPs[w*16 + mm][g8];
    v8s pa1 = *(const v8s*)&QPs[w*16 + mm][32 + g8];
#pragma unroll
    for (int n = 0; n < 8; n++){
      v8s vb0 = *(const v8s*)&Vs[n*16 + mm][g8];
      v8s vb1 = *(const v8s*)&Vs[n*16 + mm][32 + g8];
      Oacc[n] = __builtin_amdgcn_mfma_f32_16x16x32_bf16(pa0, vb0, Oacc[n], 0, 0, 0);
      Oacc[n] = __builtin_amdgcn_mfma_f32_16x16x32_bf16(pa1, vb1, Oacc[n], 0, 0, 0);
    }
  }

  float inv_l[4];
#pragma unroll
  for (int r = 0; r < 4; r++) inv_l[r] = 1.0f / l_i[r];
#pragma unroll
  for (int n = 0; n < 8; n++)
#pragma unroll
    for (int r = 0; r < 4; r++){
      int srow = q0 + w*16 + g*4 + r;
      Att[((size_t)h * S_LEN + srow) * DVV + n*16 + mm] = Oacc[n][r] * inv_l[r];
    }
}

// a = att[h] - lam*att[h+16]; RMS over 128; scale; write bf16 Ctx (S, 16*128)
__global__ __launch_bounds__(128) void diff_rms(const float* __restrict__ Att,
    const float* __restrict__ lq1, const float* __restrict__ lk1,
    const float* __restrict__ lq2, const float* __restrict__ lk2,
    u16* __restrict__ Ctx)
{
  __shared__ float lamS;
  __shared__ float red[2];
  const int blk = blockIdx.x;
  const int h = blk & 15;
  const int s = blk >> 4;
  const int d = threadIdx.x;
  if (d < 64){
    float p1 = lq1[d] * lk1[d];
    float p2 = lq2[d] * lk2[d];
#pragma unroll
    for (int off = 32; off; off >>= 1){
      p1 += __shfl_down(p1, off);
      p2 += __shfl_down(p2, off);
    }
    if (d == 0) lamS = __expf(p1) - __expf(p2) + LAMBDA_INIT;
  }
  __syncthreads();
  const float lam = lamS;
  float a = Att[((size_t)h * S_LEN + s) * DVV + d]
          - lam * Att[((size_t)(h+16) * S_LEN + s) * DVV + d];
  float ss = a * a;
#pragma unroll
  for (int off = 32; off; off >>= 1) ss += __shfl_down(ss, off);
  if ((d & 63) == 0) red[d >> 6] = ss;
  __syncthreads();
  float tot = red[0] + red[1];
  float rinv = rsqrtf(tot * (1.0f/128.0f) + 1e-6f);
  Ctx[(size_t)s * HID + h * DVV + d] = f2b(ONE_MINUS_LI * a * rinv);
}

extern "C" void kernel_launch(void* const* d_in, const int* in_sizes, int n_in,
                              void* d_out, int out_size, void* d_ws, size_t ws_size,
                              hipStream_t stream)
{
  (void)in_sizes; (void)n_in; (void)out_size; (void)ws_size;
  const float* hs   = (const float*)d_in[0];
  const float* cosb = (const float*)d_in[1];
  const float* sinb = (const float*)d_in[2];
  const float* Wq   = (const float*)d_in[3];
  const float* Wk   = (const float*)d_in[4];
  const float* Wv   = (const float*)d_in[5];
  const float* Wo   = (const float*)d_in[6];
  const float* lq1  = (const float*)d_in[7];
  const float* lk1  = (const float*)d_in[8];
  const float* lq2  = (const float*)d_in[9];
  const float* lk2  = (const float*)d_in[10];

  char* ws = (char*)d_ws;
  u16*   hsb    = (u16*)(ws);                      // [0,8) MB bf16 hs
  u16*   Wqkvb  = (u16*)(ws + (8u  << 20));        // [8,20) bf16 [Wq;Wk;Wv] 3072x2048
  float* QKVb   = (float*)(ws + (20u << 20));      // [20,44) fp32 (S,3072)
  u16*   Kbf    = (u16*)(ws + (44u << 20));        // [44,46) bf16 (8,S,64)
  u16*   Vt     = (u16*)(ws + (46u << 20));        // [46,48) bf16 (8,64,S)
  u16*   Qbf    = (u16*)(ws + (48u << 20));        // [48,56) bf16 (32,S,64)
  float* Att    = (float*)(ws);                    // [0,32) fp32, overlays dead hsb/Wqkvb/QKVb
  u16*   Ctx    = (u16*)(ws + (32u << 20));        // [32,40) bf16 (S,2048)
  u16*   Wob    = (u16*)(ws + (40u << 20));        // [40,48) bf16, after attn Kbf/Vt dead

  cast_bf16<<<2048, 256, 0, stream>>>(hs, hsb, 2048 * 2048);
  cast_bf16<<<2048, 256, 0, stream>>>(Wq, Wqkvb, 2048 * 2048);
  cast_bf16<<<512, 256, 0, stream>>>(Wk, Wqkvb + 2048 * 2048, 512 * 2048);
  cast_bf16<<<512, 256, 0, stream>>>(Wv, Wqkvb + 2560 * 2048, 512 * 2048);
  gemm_bf16<<<dim3(24, 16), 256, 0, stream>>>(hsb, Wqkvb, QKVb, S_LEN, 3072, HID);
  rope_pack<<<2048, 256, 0, stream>>>(QKVb + 2048, 3072, cosb, sinb, Kbf, NKV);
  vtrans<<<NKV * (S_LEN/64), 256, 0, stream>>>(QKVb + 2560, 3072, Vt);
  rope_pack<<<8192, 256, 0, stream>>>(QKVb, 3072, cosb, sinb, Qbf, NH);
  attn_mfma<<<dim3(S_LEN/64, NH), 256, 0, stream>>>(Qbf, Kbf, Vt, Att);
  cast_bf16<<<2048, 256, 0, stream>>>(Wo, Wob, 2048 * 2048);
  diff_rms<<<16 * S_LEN, 128, 0, stream>>>(Att, lq1, lk1, lq2, lk2, Ctx);
  gemm_bf16<<<dim3(16, 16), 256, 0, stream>>>(Ctx, Wob, (float*)d_out, S_LEN, 2048, HID);
}

// Round 7
// 295.980 us; speedup vs baseline: 8.8273x; 1.5393x over previous
//
#include <hip/hip_runtime.h>

typedef unsigned short u16;
typedef __attribute__((ext_vector_type(8))) short v8s;
typedef __attribute__((ext_vector_type(4))) float v4f;

#define S_LEN 2048
#define HID   2048
#define NH    32
#define NKV   8
#define HD    64
#define DVV   128
#define LAMBDA_INIT  0.7455692280263525f
#define ONE_MINUS_LI 0.2544307719736475f

__device__ __forceinline__ u16 f2b(float f){
  union { float f; unsigned int i; } v; v.f = f;
  unsigned int x = v.i;
  unsigned int r = (x + 0x7fffu + ((x >> 16) & 1u)) >> 16;
  return (u16)r;
}

__device__ __forceinline__ void gld16(const u16* g, u16* l){
  __builtin_amdgcn_global_load_lds(
      (const __attribute__((address_space(1))) unsigned int*)g,
      (__attribute__((address_space(3))) unsigned int*)l, 16, 0, 0);
}

// fp32 -> bf16 cast, 8 elems/thread
__global__ __launch_bounds__(256) void cast_bf16(const float* __restrict__ X, u16* __restrict__ Y, int n)
{
  int i = (blockIdx.x * 256 + threadIdx.x) * 8;
  if (i >= n) return;
  float4 a = *(const float4*)(X + i);
  float4 b = *(const float4*)(X + i + 4);
  u16 o[8] = {f2b(a.x), f2b(a.y), f2b(a.z), f2b(a.w), f2b(b.x), f2b(b.y), f2b(b.z), f2b(b.w)};
  *(uint4*)(Y + i) = *(const uint4*)o;
}

// C[m][n] = sum_k A[m*K+k]*B[n*K+k]; A,B bf16; C fp32. 128x128 tile, BK=64,
// global_load_lds staging with XOR chunk swizzle (row&7).
__global__ __launch_bounds__(256) void gemm_bf16(const u16* __restrict__ A, const u16* __restrict__ B,
                                                 float* __restrict__ C, int M, int N, int K)
{
  __shared__ __attribute__((aligned(16))) u16 As[128*64];
  __shared__ __attribute__((aligned(16))) u16 Bs[128*64];
  const int t    = threadIdx.x;
  const int w    = t >> 6, lane = t & 63;
  const int mm   = lane & 15, g = lane >> 4;
  const int wr   = w >> 1, wc = w & 1;
  const int m0   = blockIdx.y * 128, n0 = blockIdx.x * 128;
  const int srow = w*32 + (lane >> 3);
  const int sch  = lane & 7;

  v4f acc[4][4];
#pragma unroll
  for (int i = 0; i < 4; i++)
#pragma unroll
    for (int j = 0; j < 4; j++) acc[i][j] = (v4f){0.f,0.f,0.f,0.f};

  for (int k0 = 0; k0 < K; k0 += 64){
    __syncthreads();
#pragma unroll
    for (int i = 0; i < 4; i++){
      int r  = srow + i*8;
      int ce = ((sch ^ (r & 7)) * 8);
      gld16(A + (size_t)(m0 + r) * K + k0 + ce, &As[w*2048 + i*512]);
      gld16(B + (size_t)(n0 + r) * K + k0 + ce, &Bs[w*2048 + i*512]);
    }
    __syncthreads();
#pragma unroll
    for (int kc = 0; kc < 2; kc++){
      v8s af[4], bf[4];
#pragma unroll
      for (int i = 0; i < 4; i++){
        int r = wr*64 + i*16 + mm;
        af[i] = *(const v8s*)&As[r*64 + (((kc*4 + g) ^ (r & 7)) * 8)];
      }
#pragma unroll
      for (int j = 0; j < 4; j++){
        int r = wc*64 + j*16 + mm;
        bf[j] = *(const v8s*)&Bs[r*64 + (((kc*4 + g) ^ (r & 7)) * 8)];
      }
#pragma unroll
      for (int i = 0; i < 4; i++)
#pragma unroll
        for (int j = 0; j < 4; j++)
          acc[i][j] = __builtin_amdgcn_mfma_f32_16x16x32_bf16(af[i], bf[j], acc[i][j], 0, 0, 0);
    }
  }
#pragma unroll
  for (int i = 0; i < 4; i++)
#pragma unroll
    for (int j = 0; j < 4; j++)
#pragma unroll
      for (int r = 0; r < 4; r++)
        C[(size_t)(m0 + wr*64 + i*16 + g*4 + r) * N + n0 + wc*64 + j*16 + mm] = acc[i][j][r];
}

// rope + cast + transpose to (nh, S, 64) bf16; X rows have stride `stride`
__global__ __launch_bounds__(256) void rope_pack(const float* __restrict__ X, int stride,
    const float* __restrict__ cosb, const float* __restrict__ sinb,
    u16* __restrict__ Y, int nh)
{
  int idx = blockIdx.x * 256 + threadIdx.x;
  int d = idx & 31;
  int h = (idx >> 5) & (nh - 1);
  int s = idx / (32 * nh);
  float c1 = cosb[s * HD + d],      s1 = sinb[s * HD + d];
  float c2 = cosb[s * HD + d + 32], s2 = sinb[s * HD + d + 32];
  size_t src = (size_t)s * stride + (size_t)h * HD + d;
  float x1 = X[src], x2 = X[src + 32];
  size_t dst = ((size_t)h * S_LEN + s) * HD + d;
  Y[dst]      = f2b(x1 * c1 - x2 * s1);
  Y[dst + 32] = f2b(x2 * c2 + x1 * s2);
}

// V fp32 rows (stride, head h at col h*64) -> Vt bf16 (8, 64, S)
__global__ __launch_bounds__(256) void vtrans(const float* __restrict__ Vb, int stride, u16* __restrict__ Vt)
{
  __shared__ u16 T[64][72];
  const int b = blockIdx.x;
  const int h = b >> 5;
  const int s0 = (b & 31) * 64;
  const int t = threadIdx.x;
#pragma unroll
  for (int i = 0; i < 4; i++){
    int u = t + i * 256;
    int r = u >> 4, c4 = (u & 15) * 4;
    float4 v = *(const float4*)&Vb[(size_t)(s0 + r) * stride + h * HD + c4];
    T[c4+0][r] = f2b(v.x); T[c4+1][r] = f2b(v.y);
    T[c4+2][r] = f2b(v.z); T[c4+3][r] = f2b(v.w);
  }
  __syncthreads();
#pragma unroll
  for (int i = 0; i < 2; i++){
    int u = t + i * 256;
    int d = u >> 3, ch = (u & 7) * 8;
    *(uint4*)&Vt[((size_t)h * HD + d) * S_LEN + s0 + ch] = *(const uint4*)&T[d][ch];
  }
}

// Fused differential flash attention: head pair (hp, hp+16) per block.
// Q (NH,S,64) K (NKV,S,64) Vt (NKV,64,S) bf16; writes diff+RMS bf16 Ctx (S, 16*128).
// Fixed-shift softmax (no online max); K/V staged via global_load_lds + XOR swizzle.
__global__ __launch_bounds__(256) void attn_fused(
    const u16* __restrict__ Qbf, const u16* __restrict__ Kbf, const u16* __restrict__ Vt,
    const float* __restrict__ lq1, const float* __restrict__ lk1,
    const float* __restrict__ lq2, const float* __restrict__ lk2,
    u16* __restrict__ Ctx)
{
  __shared__ u16 QPa[64][72];                                 // Q tile then P tile, head a
  __shared__ u16 QPb[64][72];                                 // head b
  __shared__ __attribute__((aligned(16))) u16 Ksa[64*64];     // unpadded, swizzled
  __shared__ __attribute__((aligned(16))) u16 Ksb[64*64];
  __shared__ __attribute__((aligned(16))) u16 Vs[128*64];     // shared by both heads

  const int hp  = blockIdx.y;                                 // 0..15
  const int q0  = (int)(gridDim.x - 1 - blockIdx.x) * 64;     // longest blocks first
  const int kva = hp >> 2, kvb = kva + 4;                     // K heads; V tile = [V[kva]|V[kvb]]
  const int t   = threadIdx.x, w = t >> 6, lane = t & 63;
  const int mm  = lane & 15, g = lane >> 4, g8 = g * 8;
  const int sr  = t >> 3;                                     // staging row 0..31
  const int sc  = t & 7;                                      // staging chunk slot
  const int so  = sc * 8;
  const int x0  = ((g ^ (mm & 7)) * 8);                       // swizzled frag chunk offs
  const int x1  = (((g + 4) ^ (mm & 7)) * 8);

  // lambda scalar (all 64 lanes)
  float lp1 = lq1[lane] * lk1[lane];
  float lp2 = lq2[lane] * lk2[lane];
#pragma unroll
  for (int off = 1; off < 64; off <<= 1){
    lp1 += __shfl_xor(lp1, off);
    lp2 += __shfl_xor(lp2, off);
  }
  const float lam = __expf(lp1) - __expf(lp2) + LAMBDA_INIT;

  // stage Q tiles (once, padded, plain stores)
#pragma unroll
  for (int i = 0; i < 2; i++){
    int r = sr + i*32;
    *(uint4*)&QPa[r][so] = *(const uint4*)&Qbf[((size_t)hp        * S_LEN + q0 + r) * HD + so];
    *(uint4*)&QPb[r][so] = *(const uint4*)&Qbf[((size_t)(hp + 16) * S_LEN + q0 + r) * HD + so];
  }
  __syncthreads();
  v8s qaa0 = *(const v8s*)&QPa[w*16 + mm][g8];
  v8s qaa1 = *(const v8s*)&QPa[w*16 + mm][32 + g8];
  v8s qab0 = *(const v8s*)&QPb[w*16 + mm][g8];
  v8s qab1 = *(const v8s*)&QPb[w*16 + mm][32 + g8];

  v4f Oa[8], Ob[8];
#pragma unroll
  for (int n = 0; n < 8; n++){ Oa[n] = (v4f){0.f,0.f,0.f,0.f}; Ob[n] = (v4f){0.f,0.f,0.f,0.f}; }
  float la[4] = {0.f,0.f,0.f,0.f}, lb[4] = {0.f,0.f,0.f,0.f};

  for (int k0 = 0; k0 <= q0; k0 += 64){
    __syncthreads();
#pragma unroll
    for (int i = 0; i < 2; i++){
      int r  = sr + i*32;
      int ce = ((sc ^ (r & 7)) * 8);
      gld16(Kbf + ((size_t)kva * S_LEN + k0 + r) * HD + ce, &Ksa[(w*8 + i*32)*64]);
      gld16(Kbf + ((size_t)kvb * S_LEN + k0 + r) * HD + ce, &Ksb[(w*8 + i*32)*64]);
    }
#pragma unroll
    for (int i = 0; i < 4; i++){
      int d    = sr + i*32;
      int head = (d < 64) ? kva : kvb;
      int ce   = ((sc ^ (d & 7)) * 8);
      gld16(Vt + ((size_t)head * HD + (d & 63)) * S_LEN + k0 + ce, &Vs[(w*8 + i*32)*64]);
    }
    __syncthreads();

    const bool dg = (k0 == q0);
    // ---- head a: QK^T + softmax -> P in QPa
    {
      v4f S[4];
#pragma unroll
      for (int n = 0; n < 4; n++){
        int row = n*16 + mm;
        v8s kb0 = *(const v8s*)&Ksa[row*64 + x0];
        v8s kb1 = *(const v8s*)&Ksa[row*64 + x1];
        v4f z = (v4f){0.f,0.f,0.f,0.f};
        z = __builtin_amdgcn_mfma_f32_16x16x32_bf16(qaa0, kb0, z, 0, 0, 0);
        z = __builtin_amdgcn_mfma_f32_16x16x32_bf16(qaa1, kb1, z, 0, 0, 0);
        S[n] = z;
      }
#pragma unroll
      for (int n = 0; n < 4; n++)
#pragma unroll
        for (int r = 0; r < 4; r++){
          float p = __expf(S[n][r] * 0.125f);
          if (dg && (n*16 + mm > w*16 + g*4 + r)) p = 0.f;
          la[r] += p;
          QPa[w*16 + g*4 + r][n*16 + mm] = f2b(p);
        }
    }
    // ---- head b
    {
      v4f S[4];
#pragma unroll
      for (int n = 0; n < 4; n++){
        int row = n*16 + mm;
        v8s kb0 = *(const v8s*)&Ksb[row*64 + x0];
        v8s kb1 = *(const v8s*)&Ksb[row*64 + x1];
        v4f z = (v4f){0.f,0.f,0.f,0.f};
        z = __builtin_amdgcn_mfma_f32_16x16x32_bf16(qab0, kb0, z, 0, 0, 0);
        z = __builtin_amdgcn_mfma_f32_16x16x32_bf16(qab1, kb1, z, 0, 0, 0);
        S[n] = z;
      }
#pragma unroll
      for (int n = 0; n < 4; n++)
#pragma unroll
        for (int r = 0; r < 4; r++){
          float p = __expf(S[n][r] * 0.125f);
          if (dg && (n*16 + mm > w*16 + g*4 + r)) p = 0.f;
          lb[r] += p;
          QPb[w*16 + g*4 + r][n*16 + mm] = f2b(p);
        }
    }
    // ---- PV for both heads, sharing V fragments
    v8s paa0 = *(const v8s*)&QPa[w*16 + mm][g8];
    v8s paa1 = *(const v8s*)&QPa[w*16 + mm][32 + g8];
    v8s pab0 = *(const v8s*)&QPb[w*16 + mm][g8];
    v8s pab1 = *(const v8s*)&QPb[w*16 + mm][32 + g8];
#pragma unroll
    for (int n = 0; n < 8; n++){
      int row = n*16 + mm;
      v8s vb0 = *(const v8s*)&Vs[row*64 + x0];
      v8s vb1 = *(const v8s*)&Vs[row*64 + x1];
      Oa[n] = __builtin_amdgcn_mfma_f32_16x16x32_bf16(paa0, vb0, Oa[n], 0, 0, 0);
      Oa[n] = __builtin_amdgcn_mfma_f32_16x16x32_bf16(paa1, vb1, Oa[n], 0, 0, 0);
      Ob[n] = __builtin_amdgcn_mfma_f32_16x16x32_bf16(pab0, vb0, Ob[n], 0, 0, 0);
      Ob[n] = __builtin_amdgcn_mfma_f32_16x16x32_bf16(pab1, vb1, Ob[n], 0, 0, 0);
    }
  }

  // row sums (over 16 lanes of same g-group)
#pragma unroll
  for (int off = 1; off < 16; off <<= 1)
#pragma unroll
    for (int r = 0; r < 4; r++){
      la[r] += __shfl_xor(la[r], off);
      lb[r] += __shfl_xor(lb[r], off);
    }
  float ila[4], ilb[4];
#pragma unroll
  for (int r = 0; r < 4; r++){ ila[r] = 1.0f / la[r]; ilb[r] = lam / lb[r]; }

  // diff + RMS + scale, write bf16 Ctx
  float av[8][4];
  float ss[4] = {0.f,0.f,0.f,0.f};
#pragma unroll
  for (int n = 0; n < 8; n++)
#pragma unroll
    for (int r = 0; r < 4; r++){
      float a = Oa[n][r] * ila[r] - Ob[n][r] * ilb[r];
      av[n][r] = a;
      ss[r] += a * a;
    }
#pragma unroll
  for (int off = 1; off < 16; off <<= 1)
#pragma unroll
    for (int r = 0; r < 4; r++)
      ss[r] += __shfl_xor(ss[r], off);
  float rv[4];
#pragma unroll
  for (int r = 0; r < 4; r++)
    rv[r] = rsqrtf(ss[r] * (1.0f/128.0f) + 1e-6f) * ONE_MINUS_LI;
#pragma unroll
  for (int n = 0; n < 8; n++)
#pragma unroll
    for (int r = 0; r < 4; r++){
      int srow = q0 + w*16 + g*4 + r;
      Ctx[(size_t)srow * HID + hp * DVV + n*16 + mm] = f2b(av[n][r] * rv[r]);
    }
}

extern "C" void kernel_launch(void* const* d_in, const int* in_sizes, int n_in,
                              void* d_out, int out_size, void* d_ws, size_t ws_size,
                              hipStream_t stream)
{
  (void)in_sizes; (void)n_in; (void)out_size; (void)ws_size;
  const float* hs   = (const float*)d_in[0];
  const float* cosb = (const float*)d_in[1];
  const float* sinb = (const float*)d_in[2];
  const float* Wq   = (const float*)d_in[3];
  const float* Wk   = (const float*)d_in[4];
  const float* Wv   = (const float*)d_in[5];
  const float* Wo   = (const float*)d_in[6];
  const float* lq1  = (const float*)d_in[7];
  const float* lk1  = (const float*)d_in[8];
  const float* lq2  = (const float*)d_in[9];
  const float* lk2  = (const float*)d_in[10];

  char* ws = (char*)d_ws;
  u16*   hsb    = (u16*)(ws);                      // [0,8) MB bf16 hs
  u16*   Wqkvb  = (u16*)(ws + (8u  << 20));        // [8,20) bf16 [Wq;Wk;Wv] 3072x2048
  float* QKVb   = (float*)(ws + (20u << 20));      // [20,44) fp32 (S,3072)
  u16*   Kbf    = (u16*)(ws + (44u << 20));        // [44,46) bf16 (8,S,64)
  u16*   Vt     = (u16*)(ws + (46u << 20));        // [46,48) bf16 (8,64,S)
  u16*   Qbf    = (u16*)(ws + (48u << 20));        // [48,56) bf16 (32,S,64)
  u16*   Ctx    = (u16*)(ws + (20u << 20));        // [20,28) bf16 (S,2048), overlays dead QKVb
  u16*   Wob    = (u16*)(ws + (28u << 20));        // [28,36) bf16 Wo, overlays dead QKVb

  cast_bf16<<<2048, 256, 0, stream>>>(hs, hsb, 2048 * 2048);
  cast_bf16<<<2048, 256, 0, stream>>>(Wq, Wqkvb, 2048 * 2048);
  cast_bf16<<<512, 256, 0, stream>>>(Wk, Wqkvb + 2048 * 2048, 512 * 2048);
  cast_bf16<<<512, 256, 0, stream>>>(Wv, Wqkvb + 2560 * 2048, 512 * 2048);
  gemm_bf16<<<dim3(24, 16), 256, 0, stream>>>(hsb, Wqkvb, QKVb, S_LEN, 3072, HID);
  rope_pack<<<2048, 256, 0, stream>>>(QKVb + 2048, 3072, cosb, sinb, Kbf, NKV);
  vtrans<<<NKV * (S_LEN/64), 256, 0, stream>>>(QKVb + 2560, 3072, Vt);
  rope_pack<<<8192, 256, 0, stream>>>(QKVb, 3072, cosb, sinb, Qbf, NH);
  attn_fused<<<dim3(S_LEN/64, NH/2), 256, 0, stream>>>(Qbf, Kbf, Vt, lq1, lk1, lq2, lk2, Ctx);
  cast_bf16<<<2048, 256, 0, stream>>>(Wo, Wob, 2048 * 2048);
  gemm_bf16<<<dim3(16, 16), 256, 0, stream>>>(Ctx, Wob, (float*)d_out, S_LEN, 2048, HID);
}

// Round 8
// 282.008 us; speedup vs baseline: 9.2647x; 1.0495x over previous
//
#include <hip/hip_runtime.h>

typedef unsigned short u16;
typedef __attribute__((ext_vector_type(8))) short v8s;
typedef __attribute__((ext_vector_type(4))) float v4f;

#define S_LEN 2048
#define HID   2048
#define NH    32
#define NKV   8
#define HD    64
#define DVV   128
#define LAMBDA_INIT  0.7455692280263525f
#define ONE_MINUS_LI 0.2544307719736475f

__device__ __forceinline__ u16 f2b(float f){
  union { float f; unsigned int i; } v; v.f = f;
  unsigned int x = v.i;
  unsigned int r = (x + 0x7fffu + ((x >> 16) & 1u)) >> 16;
  return (u16)r;
}
__device__ __forceinline__ float b2f(u16 u){
  union { unsigned int i; float f; } v; v.i = ((unsigned int)u) << 16; return v.f;
}

__device__ __forceinline__ void gld16(const u16* g, u16* l){
  __builtin_amdgcn_global_load_lds(
      (const __attribute__((address_space(1))) unsigned int*)g,
      (__attribute__((address_space(3))) unsigned int*)l, 16, 0, 0);
}

// one launch casting hs, Wq, Wk, Wv, Wo to bf16 (regions by blockIdx)
__global__ __launch_bounds__(256) void cast5(
    const float* __restrict__ hs, const float* __restrict__ Wq,
    const float* __restrict__ Wk, const float* __restrict__ Wv,
    const float* __restrict__ Wo,
    u16* __restrict__ hsb, u16* __restrict__ Wqkvb, u16* __restrict__ Wob)
{
  int b = blockIdx.x;
  const float* S; u16* D; int rb;
  if (b < 2048)      { S = hs; D = hsb;             rb = b; }
  else if (b < 4096) { S = Wq; D = Wqkvb;           rb = b - 2048; }
  else if (b < 4608) { S = Wk; D = Wqkvb + 4194304; rb = b - 4096; }
  else if (b < 5120) { S = Wv; D = Wqkvb + 5242880; rb = b - 4608; }
  else               { S = Wo; D = Wob;             rb = b - 5120; }
  size_t i = ((size_t)rb * 256 + threadIdx.x) * 8;
  float4 a = *(const float4*)(S + i);
  float4 c = *(const float4*)(S + i + 4);
  u16 o[8] = {f2b(a.x), f2b(a.y), f2b(a.z), f2b(a.w), f2b(c.x), f2b(c.y), f2b(c.z), f2b(c.w)};
  *(uint4*)(D + i) = *(const uint4*)o;
}

// C[m][n] = sum_k A[m*K+k]*B[n*K+k]; A,B bf16; C fp32 or bf16. 128x128 tile, BK=64,
// global_load_lds staging with XOR chunk swizzle (row&7).
template<int OUT_BF16>
__global__ __launch_bounds__(256) void gemm_bf16(const u16* __restrict__ A, const u16* __restrict__ B,
                                                 void* __restrict__ Cv, int M, int N, int K)
{
  __shared__ __attribute__((aligned(16))) u16 As[128*64];
  __shared__ __attribute__((aligned(16))) u16 Bs[128*64];
  const int t    = threadIdx.x;
  const int w    = t >> 6, lane = t & 63;
  const int mm   = lane & 15, g = lane >> 4;
  const int wr   = w >> 1, wc = w & 1;
  const int m0   = blockIdx.y * 128, n0 = blockIdx.x * 128;
  const int srow = w*32 + (lane >> 3);
  const int sch  = lane & 7;

  v4f acc[4][4];
#pragma unroll
  for (int i = 0; i < 4; i++)
#pragma unroll
    for (int j = 0; j < 4; j++) acc[i][j] = (v4f){0.f,0.f,0.f,0.f};

  for (int k0 = 0; k0 < K; k0 += 64){
    __syncthreads();
#pragma unroll
    for (int i = 0; i < 4; i++){
      int r  = srow + i*8;
      int ce = ((sch ^ (r & 7)) * 8);
      gld16(A + (size_t)(m0 + r) * K + k0 + ce, &As[w*2048 + i*512]);
      gld16(B + (size_t)(n0 + r) * K + k0 + ce, &Bs[w*2048 + i*512]);
    }
    __syncthreads();
#pragma unroll
    for (int kc = 0; kc < 2; kc++){
      v8s af[4], bf[4];
#pragma unroll
      for (int i = 0; i < 4; i++){
        int r = wr*64 + i*16 + mm;
        af[i] = *(const v8s*)&As[r*64 + (((kc*4 + g) ^ (r & 7)) * 8)];
      }
#pragma unroll
      for (int j = 0; j < 4; j++){
        int r = wc*64 + j*16 + mm;
        bf[j] = *(const v8s*)&Bs[r*64 + (((kc*4 + g) ^ (r & 7)) * 8)];
      }
#pragma unroll
      for (int i = 0; i < 4; i++)
#pragma unroll
        for (int j = 0; j < 4; j++)
          acc[i][j] = __builtin_amdgcn_mfma_f32_16x16x32_bf16(af[i], bf[j], acc[i][j], 0, 0, 0);
    }
  }
  if (OUT_BF16){
    u16* C = (u16*)Cv;
#pragma unroll
    for (int i = 0; i < 4; i++)
#pragma unroll
      for (int j = 0; j < 4; j++)
#pragma unroll
        for (int r = 0; r < 4; r++)
          C[(size_t)(m0 + wr*64 + i*16 + g*4 + r) * N + n0 + wc*64 + j*16 + mm] = f2b(acc[i][j][r]);
  } else {
    float* C = (float*)Cv;
#pragma unroll
    for (int i = 0; i < 4; i++)
#pragma unroll
      for (int j = 0; j < 4; j++)
#pragma unroll
        for (int r = 0; r < 4; r++)
          C[(size_t)(m0 + wr*64 + i*16 + g*4 + r) * N + n0 + wc*64 + j*16 + mm] = acc[i][j][r];
  }
}

// rope on bf16 input rows (stride u16 elems) -> (nh, S, 64) bf16
__global__ __launch_bounds__(256) void rope_pack(const u16* __restrict__ X, int stride,
    const float* __restrict__ cosb, const float* __restrict__ sinb,
    u16* __restrict__ Y, int nh)
{
  int idx = blockIdx.x * 256 + threadIdx.x;
  int d = idx & 31;
  int h = (idx >> 5) & (nh - 1);
  int s = idx / (32 * nh);
  float c1 = cosb[s * HD + d],      s1 = sinb[s * HD + d];
  float c2 = cosb[s * HD + d + 32], s2 = sinb[s * HD + d + 32];
  size_t src = (size_t)s * stride + (size_t)h * HD + d;
  float x1 = b2f(X[src]), x2 = b2f(X[src + 32]);
  size_t dst = ((size_t)h * S_LEN + s) * HD + d;
  Y[dst]      = f2b(x1 * c1 - x2 * s1);
  Y[dst + 32] = f2b(x2 * c2 + x1 * s2);
}

// V bf16 rows (stride u16 elems, head h at col h*64) -> Vt bf16 (8, 64, S)
__global__ __launch_bounds__(256) void vtrans(const u16* __restrict__ Vb, int stride, u16* __restrict__ Vt)
{
  __shared__ u16 T[64][72];
  const int b = blockIdx.x;
  const int h = b >> 5;
  const int s0 = (b & 31) * 64;
  const int t = threadIdx.x;
#pragma unroll
  for (int i = 0; i < 4; i++){
    int u = t + i * 256;
    int r = u >> 4, c4 = (u & 15) * 4;
    uint2 v = *(const uint2*)&Vb[(size_t)(s0 + r) * stride + h * HD + c4];
    T[c4+0][r] = (u16)(v.x & 0xffff); T[c4+1][r] = (u16)(v.x >> 16);
    T[c4+2][r] = (u16)(v.y & 0xffff); T[c4+3][r] = (u16)(v.y >> 16);
  }
  __syncthreads();
#pragma unroll
  for (int i = 0; i < 2; i++){
    int u = t + i * 256;
    int d = u >> 3, ch = (u & 7) * 8;
    *(uint4*)&Vt[((size_t)h * HD + d) * S_LEN + s0 + ch] = *(const uint4*)&T[d][ch];
  }
}

// Fused differential flash attention, software-pipelined:
// K double-buffered (prefetch before QK), V issued at iter top, 2 barriers/iter.
__global__ __launch_bounds__(256) void attn_fused(
    const u16* __restrict__ Qbf, const u16* __restrict__ Kbf, const u16* __restrict__ Vt,
    const float* __restrict__ lq1, const float* __restrict__ lk1,
    const float* __restrict__ lq2, const float* __restrict__ lk2,
    u16* __restrict__ Ctx)
{
  __shared__ u16 QPa[64][72];
  __shared__ u16 QPb[64][72];
  __shared__ __attribute__((aligned(16))) u16 Ksa[2][64*64];
  __shared__ __attribute__((aligned(16))) u16 Ksb[2][64*64];
  __shared__ __attribute__((aligned(16))) u16 Vs[128*64];

  const int hp  = blockIdx.y;
  const int q0  = (int)(gridDim.x - 1 - blockIdx.x) * 64;
  const int kva = hp >> 2, kvb = kva + 4;
  const int t   = threadIdx.x, w = t >> 6, lane = t & 63;
  const int mm  = lane & 15, g = lane >> 4, g8 = g * 8;
  const int sr  = t >> 3;
  const int sc  = t & 7;
  const int so  = sc * 8;
  const int x0  = ((g ^ (mm & 7)) * 8);
  const int x1  = (((g + 4) ^ (mm & 7)) * 8);

  float lp1 = lq1[lane] * lk1[lane];
  float lp2 = lq2[lane] * lk2[lane];
#pragma unroll
  for (int off = 1; off < 64; off <<= 1){
    lp1 += __shfl_xor(lp1, off);
    lp2 += __shfl_xor(lp2, off);
  }
  const float lam = __expf(lp1) - __expf(lp2) + LAMBDA_INIT;

  // issue K(0) async, then stage Q with plain stores
#pragma unroll
  for (int i = 0; i < 2; i++){
    int r  = sr + i*32;
    int ce = ((sc ^ (r & 7)) * 8);
    gld16(Kbf + ((size_t)kva * S_LEN + r) * HD + ce, &Ksa[0][(w*8 + i*32)*64]);
    gld16(Kbf + ((size_t)kvb * S_LEN + r) * HD + ce, &Ksb[0][(w*8 + i*32)*64]);
  }
#pragma unroll
  for (int i = 0; i < 2; i++){
    int r = sr + i*32;
    *(uint4*)&QPa[r][so] = *(const uint4*)&Qbf[((size_t)hp        * S_LEN + q0 + r) * HD + so];
    *(uint4*)&QPb[r][so] = *(const uint4*)&Qbf[((size_t)(hp + 16) * S_LEN + q0 + r) * HD + so];
  }
  __syncthreads();          // Q visible, K(0) drained
  v8s qaa0 = *(const v8s*)&QPa[w*16 + mm][g8];
  v8s qaa1 = *(const v8s*)&QPa[w*16 + mm][32 + g8];
  v8s qab0 = *(const v8s*)&QPb[w*16 + mm][g8];
  v8s qab1 = *(const v8s*)&QPb[w*16 + mm][32 + g8];

  v4f Oa[8], Ob[8];
#pragma unroll
  for (int n = 0; n < 8; n++){ Oa[n] = (v4f){0.f,0.f,0.f,0.f}; Ob[n] = (v4f){0.f,0.f,0.f,0.f}; }
  float la[4] = {0.f,0.f,0.f,0.f}, lb[4] = {0.f,0.f,0.f,0.f};

  for (int k0 = 0; k0 <= q0; k0 += 64){
    const int cur = (k0 >> 6) & 1;
    if (k0) __syncthreads();            // (1) prior PV done with Vs / prior QK done with Ks[cur^1]
    // issue V(k0) — drains behind QK+softmax
#pragma unroll
    for (int i = 0; i < 4; i++){
      int d    = sr + i*32;
      int head = (d < 64) ? kva : kvb;
      int ce   = ((sc ^ (d & 7)) * 8);
      gld16(Vt + ((size_t)head * HD + (d & 63)) * S_LEN + k0 + ce, &Vs[(w*8 + i*32)*64]);
    }
    // prefetch K(k0+64) into other buffer
    if (k0 + 64 <= q0){
#pragma unroll
      for (int i = 0; i < 2; i++){
        int r  = sr + i*32;
        int ce = ((sc ^ (r & 7)) * 8);
        gld16(Kbf + ((size_t)kva * S_LEN + k0 + 64 + r) * HD + ce, &Ksa[cur^1][(w*8 + i*32)*64]);
        gld16(Kbf + ((size_t)kvb * S_LEN + k0 + 64 + r) * HD + ce, &Ksb[cur^1][(w*8 + i*32)*64]);
      }
    }

    const bool dg = (k0 == q0);
    // head a
    {
      v4f S[4];
#pragma unroll
      for (int n = 0; n < 4; n++){
        int row = n*16 + mm;
        v8s kb0 = *(const v8s*)&Ksa[cur][row*64 + x0];
        v8s kb1 = *(const v8s*)&Ksa[cur][row*64 + x1];
        v4f z = (v4f){0.f,0.f,0.f,0.f};
        z = __builtin_amdgcn_mfma_f32_16x16x32_bf16(qaa0, kb0, z, 0, 0, 0);
        z = __builtin_amdgcn_mfma_f32_16x16x32_bf16(qaa1, kb1, z, 0, 0, 0);
        S[n] = z;
      }
#pragma unroll
      for (int n = 0; n < 4; n++)
#pragma unroll
        for (int r = 0; r < 4; r++){
          float p = __expf(S[n][r] * 0.125f);
          if (dg && (n*16 + mm > w*16 + g*4 + r)) p = 0.f;
          la[r] += p;
          QPa[w*16 + g*4 + r][n*16 + mm] = f2b(p);
        }
    }
    // head b
    {
      v4f S[4];
#pragma unroll
      for (int n = 0; n < 4; n++){
        int row = n*16 + mm;
        v8s kb0 = *(const v8s*)&Ksb[cur][row*64 + x0];
        v8s kb1 = *(const v8s*)&Ksb[cur][row*64 + x1];
        v4f z = (v4f){0.f,0.f,0.f,0.f};
        z = __builtin_amdgcn_mfma_f32_16x16x32_bf16(qab0, kb0, z, 0, 0, 0);
        z = __builtin_amdgcn_mfma_f32_16x16x32_bf16(qab1, kb1, z, 0, 0, 0);
        S[n] = z;
      }
#pragma unroll
      for (int n = 0; n < 4; n++)
#pragma unroll
        for (int r = 0; r < 4; r++){
          float p = __expf(S[n][r] * 0.125f);
          if (dg && (n*16 + mm > w*16 + g*4 + r)) p = 0.f;
          lb[r] += p;
          QPb[w*16 + g*4 + r][n*16 + mm] = f2b(p);
        }
    }
    __syncthreads();                    // (2) V staged (issued ~800 cyc ago)
    v8s paa0 = *(const v8s*)&QPa[w*16 + mm][g8];
    v8s paa1 = *(const v8s*)&QPa[w*16 + mm][32 + g8];
    v8s pab0 = *(const v8s*)&QPb[w*16 + mm][g8];
    v8s pab1 = *(const v8s*)&QPb[w*16 + mm][32 + g8];
#pragma unroll
    for (int n = 0; n < 8; n++){
      int row = n*16 + mm;
      v8s vb0 = *(const v8s*)&Vs[row*64 + x0];
      v8s vb1 = *(const v8s*)&Vs[row*64 + x1];
      Oa[n] = __builtin_amdgcn_mfma_f32_16x16x32_bf16(paa0, vb0, Oa[n], 0, 0, 0);
      Oa[n] = __builtin_amdgcn_mfma_f32_16x16x32_bf16(paa1, vb1, Oa[n], 0, 0, 0);
      Ob[n] = __builtin_amdgcn_mfma_f32_16x16x32_bf16(pab0, vb0, Ob[n], 0, 0, 0);
      Ob[n] = __builtin_amdgcn_mfma_f32_16x16x32_bf16(pab1, vb1, Ob[n], 0, 0, 0);
    }
  }

#pragma unroll
  for (int off = 1; off < 16; off <<= 1)
#pragma unroll
    for (int r = 0; r < 4; r++){
      la[r] += __shfl_xor(la[r], off);
      lb[r] += __shfl_xor(lb[r], off);
    }
  float ila[4], ilb[4];
#pragma unroll
  for (int r = 0; r < 4; r++){ ila[r] = 1.0f / la[r]; ilb[r] = lam / lb[r]; }

  float av[8][4];
  float ss[4] = {0.f,0.f,0.f,0.f};
#pragma unroll
  for (int n = 0; n < 8; n++)
#pragma unroll
    for (int r = 0; r < 4; r++){
      float a = Oa[n][r] * ila[r] - Ob[n][r] * ilb[r];
      av[n][r] = a;
      ss[r] += a * a;
    }
#pragma unroll
  for (int off = 1; off < 16; off <<= 1)
#pragma unroll
    for (int r = 0; r < 4; r++)
      ss[r] += __shfl_xor(ss[r], off);
  float rv[4];
#pragma unroll
  for (int r = 0; r < 4; r++)
    rv[r] = rsqrtf(ss[r] * (1.0f/128.0f) + 1e-6f) * ONE_MINUS_LI;
#pragma unroll
  for (int n = 0; n < 8; n++)
#pragma unroll
    for (int r = 0; r < 4; r++){
      int srow = q0 + w*16 + g*4 + r;
      Ctx[(size_t)srow * HID + hp * DVV + n*16 + mm] = f2b(av[n][r] * rv[r]);
    }
}

extern "C" void kernel_launch(void* const* d_in, const int* in_sizes, int n_in,
                              void* d_out, int out_size, void* d_ws, size_t ws_size,
                              hipStream_t stream)
{
  (void)in_sizes; (void)n_in; (void)out_size; (void)ws_size;
  const float* hs   = (const float*)d_in[0];
  const float* cosb = (const float*)d_in[1];
  const float* sinb = (const float*)d_in[2];
  const float* Wq   = (const float*)d_in[3];
  const float* Wk   = (const float*)d_in[4];
  const float* Wv   = (const float*)d_in[5];
  const float* Wo   = (const float*)d_in[6];
  const float* lq1  = (const float*)d_in[7];
  const float* lk1  = (const float*)d_in[8];
  const float* lq2  = (const float*)d_in[9];
  const float* lk2  = (const float*)d_in[10];

  char* ws = (char*)d_ws;
  u16* hsb   = (u16*)(ws);                   // [0,8) MB bf16 hs
  u16* Wqkvb = (u16*)(ws + (8u  << 20));     // [8,20) bf16 [Wq;Wk;Wv] 3072x2048
  u16* QKVb  = (u16*)(ws + (20u << 20));     // [20,32) bf16 (S,3072)
  u16* Ctx   = (u16*)(ws + (20u << 20));     // [20,28) overlays QKVb after rope/vtrans
  u16* Wob   = (u16*)(ws + (32u << 20));     // [32,40) bf16 Wo
  u16* Kbf   = (u16*)(ws + (44u << 20));     // [44,46) bf16 (8,S,64)
  u16* Vt    = (u16*)(ws + (46u << 20));     // [46,48) bf16 (8,64,S)
  u16* Qbf   = (u16*)(ws + (48u << 20));     // [48,56) bf16 (32,S,64)

  cast5<<<7168, 256, 0, stream>>>(hs, Wq, Wk, Wv, Wo, hsb, Wqkvb, Wob);
  gemm_bf16<1><<<dim3(24, 16), 256, 0, stream>>>(hsb, Wqkvb, QKVb, S_LEN, 3072, HID);
  rope_pack<<<2048, 256, 0, stream>>>(QKVb + 2048, 3072, cosb, sinb, Kbf, NKV);
  vtrans<<<NKV * (S_LEN/64), 256, 0, stream>>>(QKVb + 2560, 3072, Vt);
  rope_pack<<<8192, 256, 0, stream>>>(QKVb, 3072, cosb, sinb, Qbf, NH);
  attn_fused<<<dim3(S_LEN/64, NH/2), 256, 0, stream>>>(Qbf, Kbf, Vt, lq1, lk1, lq2, lk2, Ctx);
  gemm_bf16<0><<<dim3(16, 16), 256, 0, stream>>>(Ctx, Wob, (float*)d_out, S_LEN, 2048, HID);
}

// Round 9
// 264.677 us; speedup vs baseline: 9.8713x; 1.0655x over previous
//
#include <hip/hip_runtime.h>

typedef unsigned short u16;
typedef __attribute__((ext_vector_type(8))) short v8s;
typedef __attribute__((ext_vector_type(4))) float v4f;

#define S_LEN 2048
#define HID   2048
#define NH    32
#define NKV   8
#define HD    64
#define DVV   128
#define LAMBDA_INIT  0.7455692280263525f
#define ONE_MINUS_LI 0.2544307719736475f

__device__ __forceinline__ u16 f2b(float f){
  union { float f; unsigned int i; } v; v.f = f;
  unsigned int x = v.i;
  unsigned int r = (x + 0x7fffu + ((x >> 16) & 1u)) >> 16;
  return (u16)r;
}
__device__ __forceinline__ float b2f(u16 u){
  union { unsigned int i; float f; } v; v.i = ((unsigned int)u) << 16; return v.f;
}

__device__ __forceinline__ void gld16(const u16* g, u16* l){
  __builtin_amdgcn_global_load_lds(
      (const __attribute__((address_space(1))) unsigned int*)g,
      (__attribute__((address_space(3))) unsigned int*)l, 16, 0, 0);
}

// one launch casting hs, Wq, Wk, Wv, Wo to bf16 (regions by blockIdx)
__global__ __launch_bounds__(256) void cast5(
    const float* __restrict__ hs, const float* __restrict__ Wq,
    const float* __restrict__ Wk, const float* __restrict__ Wv,
    const float* __restrict__ Wo,
    u16* __restrict__ hsb, u16* __restrict__ Wqkvb, u16* __restrict__ Wob)
{
  int b = blockIdx.x;
  const float* S; u16* D; int rb;
  if (b < 2048)      { S = hs; D = hsb;             rb = b; }
  else if (b < 4096) { S = Wq; D = Wqkvb;           rb = b - 2048; }
  else if (b < 4608) { S = Wk; D = Wqkvb + 4194304; rb = b - 4096; }
  else if (b < 5120) { S = Wv; D = Wqkvb + 5242880; rb = b - 4608; }
  else               { S = Wo; D = Wob;             rb = b - 5120; }
  size_t i = ((size_t)rb * 256 + threadIdx.x) * 8;
  float4 a = *(const float4*)(S + i);
  float4 c = *(const float4*)(S + i + 4);
  u16 o[8] = {f2b(a.x), f2b(a.y), f2b(a.z), f2b(a.w), f2b(c.x), f2b(c.y), f2b(c.z), f2b(c.w)};
  *(uint4*)(D + i) = *(const uint4*)o;
}

// C[m][n] = sum_k A[m*K+k]*B[n*K+k]; A,B bf16; C fp32 or bf16. 128x128 tile, BK=64,
// global_load_lds staging with XOR chunk swizzle (row&7).
template<int OUT_BF16>
__global__ __launch_bounds__(256) void gemm_bf16(const u16* __restrict__ A, const u16* __restrict__ B,
                                                 void* __restrict__ Cv, int M, int N, int K)
{
  __shared__ __attribute__((aligned(16))) u16 As[128*64];
  __shared__ __attribute__((aligned(16))) u16 Bs[128*64];
  const int t    = threadIdx.x;
  const int w    = t >> 6, lane = t & 63;
  const int mm   = lane & 15, g = lane >> 4;
  const int wr   = w >> 1, wc = w & 1;
  const int m0   = blockIdx.y * 128, n0 = blockIdx.x * 128;
  const int srow = w*32 + (lane >> 3);
  const int sch  = lane & 7;

  v4f acc[4][4];
#pragma unroll
  for (int i = 0; i < 4; i++)
#pragma unroll
    for (int j = 0; j < 4; j++) acc[i][j] = (v4f){0.f,0.f,0.f,0.f};

  for (int k0 = 0; k0 < K; k0 += 64){
    __syncthreads();
#pragma unroll
    for (int i = 0; i < 4; i++){
      int r  = srow + i*8;
      int ce = ((sch ^ (r & 7)) * 8);
      gld16(A + (size_t)(m0 + r) * K + k0 + ce, &As[w*2048 + i*512]);
      gld16(B + (size_t)(n0 + r) * K + k0 + ce, &Bs[w*2048 + i*512]);
    }
    __syncthreads();
#pragma unroll
    for (int kc = 0; kc < 2; kc++){
      v8s af[4], bf[4];
#pragma unroll
      for (int i = 0; i < 4; i++){
        int r = wr*64 + i*16 + mm;
        af[i] = *(const v8s*)&As[r*64 + (((kc*4 + g) ^ (r & 7)) * 8)];
      }
#pragma unroll
      for (int j = 0; j < 4; j++){
        int r = wc*64 + j*16 + mm;
        bf[j] = *(const v8s*)&Bs[r*64 + (((kc*4 + g) ^ (r & 7)) * 8)];
      }
#pragma unroll
      for (int i = 0; i < 4; i++)
#pragma unroll
        for (int j = 0; j < 4; j++)
          acc[i][j] = __builtin_amdgcn_mfma_f32_16x16x32_bf16(af[i], bf[j], acc[i][j], 0, 0, 0);
    }
  }
  if (OUT_BF16){
    u16* C = (u16*)Cv;
#pragma unroll
    for (int i = 0; i < 4; i++)
#pragma unroll
      for (int j = 0; j < 4; j++)
#pragma unroll
        for (int r = 0; r < 4; r++)
          C[(size_t)(m0 + wr*64 + i*16 + g*4 + r) * N + n0 + wc*64 + j*16 + mm] = f2b(acc[i][j][r]);
  } else {
    float* C = (float*)Cv;
#pragma unroll
    for (int i = 0; i < 4; i++)
#pragma unroll
      for (int j = 0; j < 4; j++)
#pragma unroll
        for (int r = 0; r < 4; r++)
          C[(size_t)(m0 + wr*64 + i*16 + g*4 + r) * N + n0 + wc*64 + j*16 + mm] = acc[i][j][r];
  }
}

// rope for Q (blocks 0..8191) and K (8192..10239) in one launch; bf16 in/out
__global__ __launch_bounds__(256) void rope_all(const u16* __restrict__ QKVb,
    const float* __restrict__ cosb, const float* __restrict__ sinb,
    u16* __restrict__ Qbf, u16* __restrict__ Kbf)
{
  int b = blockIdx.x;
  int d, h, s;
  const u16* src; u16* dst;
  if (b < 8192){
    int idx = b * 256 + threadIdx.x;
    d = idx & 31; h = (idx >> 5) & 31; s = idx >> 10;
    src = QKVb + (size_t)s * 3072 + h * HD + d;
    dst = Qbf + ((size_t)h * S_LEN + s) * HD + d;
  } else {
    int idx = (b - 8192) * 256 + threadIdx.x;
    d = idx & 31; h = (idx >> 5) & 7; s = idx >> 8;
    src = QKVb + (size_t)s * 3072 + 2048 + h * HD + d;
    dst = Kbf + ((size_t)h * S_LEN + s) * HD + d;
  }
  float c1 = cosb[s * HD + d],      s1 = sinb[s * HD + d];
  float c2 = cosb[s * HD + d + 32], s2 = sinb[s * HD + d + 32];
  float x1 = b2f(src[0]), x2 = b2f(src[32]);
  dst[0]  = f2b(x1 * c1 - x2 * s1);
  dst[32] = f2b(x2 * c2 + x1 * s2);
}

// V bf16 rows (stride u16 elems, head h at col h*64) -> Vt bf16 (8, 64, S)
__global__ __launch_bounds__(256) void vtrans(const u16* __restrict__ Vb, int stride, u16* __restrict__ Vt)
{
  __shared__ u16 T[64][72];
  const int b = blockIdx.x;
  const int h = b >> 5;
  const int s0 = (b & 31) * 64;
  const int t = threadIdx.x;
#pragma unroll
  for (int i = 0; i < 4; i++){
    int u = t + i * 256;
    int r = u >> 4, c4 = (u & 15) * 4;
    uint2 v = *(const uint2*)&Vb[(size_t)(s0 + r) * stride + h * HD + c4];
    T[c4+0][r] = (u16)(v.x & 0xffff); T[c4+1][r] = (u16)(v.x >> 16);
    T[c4+2][r] = (u16)(v.y & 0xffff); T[c4+3][r] = (u16)(v.y >> 16);
  }
  __syncthreads();
#pragma unroll
  for (int i = 0; i < 2; i++){
    int u = t + i * 256;
    int d = u >> 3, ch = (u & 7) * 8;
    *(uint4*)&Vt[((size_t)h * HD + d) * S_LEN + s0 + ch] = *(const uint4*)&T[d][ch];
  }
}

// Fused differential flash attention, uniform-work blocks:
// block (p, hp) processes q-tiles 31-p then p as chained segments -> 33 k-iters for all blocks.
__global__ __launch_bounds__(256) void attn_fused(
    const u16* __restrict__ Qbf, const u16* __restrict__ Kbf, const u16* __restrict__ Vt,
    const float* __restrict__ lq1, const float* __restrict__ lk1,
    const float* __restrict__ lq2, const float* __restrict__ lk2,
    u16* __restrict__ Ctx)
{
  __shared__ u16 QPa[64][72];
  __shared__ u16 QPb[64][72];
  __shared__ __attribute__((aligned(16))) u16 Ksa[2][64*64];
  __shared__ __attribute__((aligned(16))) u16 Ksb[2][64*64];
  __shared__ __attribute__((aligned(16))) u16 Vs[128*64];

  const int p   = blockIdx.x;                 // 0..15
  const int hp  = blockIdx.y;                 // 0..15
  const int kva = hp >> 2, kvb = kva + 4;
  const int t   = threadIdx.x, w = t >> 6, lane = t & 63;
  const int mm  = lane & 15, g = lane >> 4, g8 = g * 8;
  const int sr  = t >> 3;
  const int sc  = t & 7;
  const int so  = sc * 8;
  const int x0  = ((g ^ (mm & 7)) * 8);
  const int x1  = (((g + 4) ^ (mm & 7)) * 8);

  float lp1 = lq1[lane] * lk1[lane];
  float lp2 = lq2[lane] * lk2[lane];
#pragma unroll
  for (int off = 1; off < 64; off <<= 1){
    lp1 += __shfl_xor(lp1, off);
    lp2 += __shfl_xor(lp2, off);
  }
  const float lam = __expf(lp1) - __expf(lp2) + LAMBDA_INIT;

  for (int seg = 0; seg < 2; seg++){
    const int qt = seg ? p : (31 - p);
    const int q0 = qt * 64;

    __syncthreads();   // protect Ks/Vs/QP restage from prior segment's readers
    // issue K(0) async, then stage Q with plain stores
#pragma unroll
    for (int i = 0; i < 2; i++){
      int r  = sr + i*32;
      int ce = ((sc ^ (r & 7)) * 8);
      gld16(Kbf + ((size_t)kva * S_LEN + r) * HD + ce, &Ksa[0][(w*8 + i*32)*64]);
      gld16(Kbf + ((size_t)kvb * S_LEN + r) * HD + ce, &Ksb[0][(w*8 + i*32)*64]);
    }
#pragma unroll
    for (int i = 0; i < 2; i++){
      int r = sr + i*32;
      *(uint4*)&QPa[r][so] = *(const uint4*)&Qbf[((size_t)hp        * S_LEN + q0 + r) * HD + so];
      *(uint4*)&QPb[r][so] = *(const uint4*)&Qbf[((size_t)(hp + 16) * S_LEN + q0 + r) * HD + so];
    }
    __syncthreads();   // Q visible, K(0) drained
    v8s qaa0 = *(const v8s*)&QPa[w*16 + mm][g8];
    v8s qaa1 = *(const v8s*)&QPa[w*16 + mm][32 + g8];
    v8s qab0 = *(const v8s*)&QPb[w*16 + mm][g8];
    v8s qab1 = *(const v8s*)&QPb[w*16 + mm][32 + g8];

    v4f Oa[8], Ob[8];
#pragma unroll
    for (int n = 0; n < 8; n++){ Oa[n] = (v4f){0.f,0.f,0.f,0.f}; Ob[n] = (v4f){0.f,0.f,0.f,0.f}; }
    float la[4] = {0.f,0.f,0.f,0.f}, lb[4] = {0.f,0.f,0.f,0.f};

    for (int k0 = 0; k0 <= q0; k0 += 64){
      const int cur = (k0 >> 6) & 1;
      if (k0) __syncthreads();          // prior PV done with Vs / prior QK done with Ks[cur^1]
      // issue V(k0) — drains behind QK+softmax
#pragma unroll
      for (int i = 0; i < 4; i++){
        int d    = sr + i*32;
        int head = (d < 64) ? kva : kvb;
        int ce   = ((sc ^ (d & 7)) * 8);
        gld16(Vt + ((size_t)head * HD + (d & 63)) * S_LEN + k0 + ce, &Vs[(w*8 + i*32)*64]);
      }
      // prefetch K(k0+64) into other buffer
      if (k0 + 64 <= q0){
#pragma unroll
        for (int i = 0; i < 2; i++){
          int r  = sr + i*32;
          int ce = ((sc ^ (r & 7)) * 8);
          gld16(Kbf + ((size_t)kva * S_LEN + k0 + 64 + r) * HD + ce, &Ksa[cur^1][(w*8 + i*32)*64]);
          gld16(Kbf + ((size_t)kvb * S_LEN + k0 + 64 + r) * HD + ce, &Ksb[cur^1][(w*8 + i*32)*64]);
        }
      }

      const bool dg = (k0 == q0);
      // head a
      {
        v4f S[4];
#pragma unroll
        for (int n = 0; n < 4; n++){
          int row = n*16 + mm;
          v8s kb0 = *(const v8s*)&Ksa[cur][row*64 + x0];
          v8s kb1 = *(const v8s*)&Ksa[cur][row*64 + x1];
          v4f z = (v4f){0.f,0.f,0.f,0.f};
          z = __builtin_amdgcn_mfma_f32_16x16x32_bf16(qaa0, kb0, z, 0, 0, 0);
          z = __builtin_amdgcn_mfma_f32_16x16x32_bf16(qaa1, kb1, z, 0, 0, 0);
          S[n] = z;
        }
#pragma unroll
        for (int n = 0; n < 4; n++)
#pragma unroll
          for (int r = 0; r < 4; r++){
            float pe = __expf(S[n][r] * 0.125f);
            if (dg && (n*16 + mm > w*16 + g*4 + r)) pe = 0.f;
            la[r] += pe;
            QPa[w*16 + g*4 + r][n*16 + mm] = f2b(pe);
          }
      }
      // head b
      {
        v4f S[4];
#pragma unroll
        for (int n = 0; n < 4; n++){
          int row = n*16 + mm;
          v8s kb0 = *(const v8s*)&Ksb[cur][row*64 + x0];
          v8s kb1 = *(const v8s*)&Ksb[cur][row*64 + x1];
          v4f z = (v4f){0.f,0.f,0.f,0.f};
          z = __builtin_amdgcn_mfma_f32_16x16x32_bf16(qab0, kb0, z, 0, 0, 0);
          z = __builtin_amdgcn_mfma_f32_16x16x32_bf16(qab1, kb1, z, 0, 0, 0);
          S[n] = z;
        }
#pragma unroll
        for (int n = 0; n < 4; n++)
#pragma unroll
          for (int r = 0; r < 4; r++){
            float pe = __expf(S[n][r] * 0.125f);
            if (dg && (n*16 + mm > w*16 + g*4 + r)) pe = 0.f;
            lb[r] += pe;
            QPb[w*16 + g*4 + r][n*16 + mm] = f2b(pe);
          }
      }
      __syncthreads();                  // V staged (issued earlier this iter)
      v8s paa0 = *(const v8s*)&QPa[w*16 + mm][g8];
      v8s paa1 = *(const v8s*)&QPa[w*16 + mm][32 + g8];
      v8s pab0 = *(const v8s*)&QPb[w*16 + mm][g8];
      v8s pab1 = *(const v8s*)&QPb[w*16 + mm][32 + g8];
#pragma unroll
      for (int n = 0; n < 8; n++){
        int row = n*16 + mm;
        v8s vb0 = *(const v8s*)&Vs[row*64 + x0];
        v8s vb1 = *(const v8s*)&Vs[row*64 + x1];
        Oa[n] = __builtin_amdgcn_mfma_f32_16x16x32_bf16(paa0, vb0, Oa[n], 0, 0, 0);
        Oa[n] = __builtin_amdgcn_mfma_f32_16x16x32_bf16(paa1, vb1, Oa[n], 0, 0, 0);
        Ob[n] = __builtin_amdgcn_mfma_f32_16x16x32_bf16(pab0, vb0, Ob[n], 0, 0, 0);
        Ob[n] = __builtin_amdgcn_mfma_f32_16x16x32_bf16(pab1, vb1, Ob[n], 0, 0, 0);
      }
    }

    // epilogue for this segment
#pragma unroll
    for (int off = 1; off < 16; off <<= 1)
#pragma unroll
      for (int r = 0; r < 4; r++){
        la[r] += __shfl_xor(la[r], off);
        lb[r] += __shfl_xor(lb[r], off);
      }
    float ila[4], ilb[4];
#pragma unroll
    for (int r = 0; r < 4; r++){ ila[r] = 1.0f / la[r]; ilb[r] = lam / lb[r]; }

    float av[8][4];
    float ss[4] = {0.f,0.f,0.f,0.f};
#pragma unroll
    for (int n = 0; n < 8; n++)
#pragma unroll
      for (int r = 0; r < 4; r++){
        float a = Oa[n][r] * ila[r] - Ob[n][r] * ilb[r];
        av[n][r] = a;
        ss[r] += a * a;
      }
#pragma unroll
    for (int off = 1; off < 16; off <<= 1)
#pragma unroll
      for (int r = 0; r < 4; r++)
        ss[r] += __shfl_xor(ss[r], off);
    float rv[4];
#pragma unroll
    for (int r = 0; r < 4; r++)
      rv[r] = rsqrtf(ss[r] * (1.0f/128.0f) + 1e-6f) * ONE_MINUS_LI;
#pragma unroll
    for (int n = 0; n < 8; n++)
#pragma unroll
      for (int r = 0; r < 4; r++){
        int srow = q0 + w*16 + g*4 + r;
        Ctx[(size_t)srow * HID + hp * DVV + n*16 + mm] = f2b(av[n][r] * rv[r]);
      }
  }
}

extern "C" void kernel_launch(void* const* d_in, const int* in_sizes, int n_in,
                              void* d_out, int out_size, void* d_ws, size_t ws_size,
                              hipStream_t stream)
{
  (void)in_sizes; (void)n_in; (void)out_size; (void)ws_size;
  const float* hs   = (const float*)d_in[0];
  const float* cosb = (const float*)d_in[1];
  const float* sinb = (const float*)d_in[2];
  const float* Wq   = (const float*)d_in[3];
  const float* Wk   = (const float*)d_in[4];
  const float* Wv   = (const float*)d_in[5];
  const float* Wo   = (const float*)d_in[6];
  const float* lq1  = (const float*)d_in[7];
  const float* lk1  = (const float*)d_in[8];
  const float* lq2  = (const float*)d_in[9];
  const float* lk2  = (const float*)d_in[10];

  char* ws = (char*)d_ws;
  u16* hsb   = (u16*)(ws);                   // [0,8) MB bf16 hs
  u16* Wqkvb = (u16*)(ws + (8u  << 20));     // [8,20) bf16 [Wq;Wk;Wv] 3072x2048
  u16* QKVb  = (u16*)(ws + (20u << 20));     // [20,32) bf16 (S,3072)
  u16* Ctx   = (u16*)(ws + (20u << 20));     // [20,28) overlays QKVb after rope/vtrans
  u16* Wob   = (u16*)(ws + (32u << 20));     // [32,40) bf16 Wo
  u16* Kbf   = (u16*)(ws + (44u << 20));     // [44,46) bf16 (8,S,64)
  u16* Vt    = (u16*)(ws + (46u << 20));     // [46,48) bf16 (8,64,S)
  u16* Qbf   = (u16*)(ws + (48u << 20));     // [48,56) bf16 (32,S,64)

  cast5<<<7168, 256, 0, stream>>>(hs, Wq, Wk, Wv, Wo, hsb, Wqkvb, Wob);
  gemm_bf16<1><<<dim3(24, 16), 256, 0, stream>>>(hsb, Wqkvb, QKVb, S_LEN, 3072, HID);
  rope_all<<<10240, 256, 0, stream>>>(QKVb, cosb, sinb, Qbf, Kbf);
  vtrans<<<NKV * (S_LEN/64), 256, 0, stream>>>(QKVb + 2560, 3072, Vt);
  attn_fused<<<dim3(16, 16), 256, 0, stream>>>(Qbf, Kbf, Vt, lq1, lk1, lq2, lk2, Ctx);
  gemm_bf16<0><<<dim3(16, 16), 256, 0, stream>>>(Ctx, Wob, (float*)d_out, S_LEN, 2048, HID);
}

// Round 10
// 252.575 us; speedup vs baseline: 10.3443x; 1.0479x over previous
//
#include <hip/hip_runtime.h>

typedef unsigned short u16;
typedef __attribute__((ext_vector_type(8))) short v8s;
typedef __attribute__((ext_vector_type(4))) float v4f;

#define S_LEN 2048
#define HID   2048
#define NH    32
#define NKV   8
#define HD    64
#define DVV   128
#define LAMBDA_INIT  0.7455692280263525f
#define ONE_MINUS_LI 0.2544307719736475f

__device__ __forceinline__ u16 f2b(float f){
  union { float f; unsigned int i; } v; v.f = f;
  unsigned int x = v.i;
  unsigned int r = (x + 0x7fffu + ((x >> 16) & 1u)) >> 16;
  return (u16)r;
}
__device__ __forceinline__ float b2f(u16 u){
  union { unsigned int i; float f; } v; v.i = ((unsigned int)u) << 16; return v.f;
}

__device__ __forceinline__ void gld16(const u16* g, u16* l){
  __builtin_amdgcn_global_load_lds(
      (const __attribute__((address_space(1))) unsigned int*)g,
      (__attribute__((address_space(3))) unsigned int*)l, 16, 0, 0);
}

// one launch casting hs, Wq, Wk, Wv, Wo to bf16 (regions by blockIdx)
__global__ __launch_bounds__(256) void cast5(
    const float* __restrict__ hs, const float* __restrict__ Wq,
    const float* __restrict__ Wk, const float* __restrict__ Wv,
    const float* __restrict__ Wo,
    u16* __restrict__ hsb, u16* __restrict__ Wqkvb, u16* __restrict__ Wob)
{
  int b = blockIdx.x;
  const float* S; u16* D; int rb;
  if (b < 2048)      { S = hs; D = hsb;             rb = b; }
  else if (b < 4096) { S = Wq; D = Wqkvb;           rb = b - 2048; }
  else if (b < 4608) { S = Wk; D = Wqkvb + 4194304; rb = b - 4096; }
  else if (b < 5120) { S = Wv; D = Wqkvb + 5242880; rb = b - 4608; }
  else               { S = Wo; D = Wob;             rb = b - 5120; }
  size_t i = ((size_t)rb * 256 + threadIdx.x) * 8;
  float4 a = *(const float4*)(S + i);
  float4 c = *(const float4*)(S + i + 4);
  u16 o[8] = {f2b(a.x), f2b(a.y), f2b(a.z), f2b(a.w), f2b(c.x), f2b(c.y), f2b(c.z), f2b(c.w)};
  *(uint4*)(D + i) = *(const uint4*)o;
}

// C[m][n] = sum_k A[m*K+k]*B[n*K+k]; A,B bf16; C fp32 or bf16. 128x128 tile, BK=64,
// global_load_lds staging with XOR chunk swizzle (row&7).
template<int OUT_BF16>
__global__ __launch_bounds__(256) void gemm_bf16(const u16* __restrict__ A, const u16* __restrict__ B,
                                                 void* __restrict__ Cv, int M, int N, int K)
{
  __shared__ __attribute__((aligned(16))) u16 As[128*64];
  __shared__ __attribute__((aligned(16))) u16 Bs[128*64];
  const int t    = threadIdx.x;
  const int w    = t >> 6, lane = t & 63;
  const int mm   = lane & 15, g = lane >> 4;
  const int wr   = w >> 1, wc = w & 1;
  const int m0   = blockIdx.y * 128, n0 = blockIdx.x * 128;
  const int srow = w*32 + (lane >> 3);
  const int sch  = lane & 7;

  v4f acc[4][4];
#pragma unroll
  for (int i = 0; i < 4; i++)
#pragma unroll
    for (int j = 0; j < 4; j++) acc[i][j] = (v4f){0.f,0.f,0.f,0.f};

  for (int k0 = 0; k0 < K; k0 += 64){
    __syncthreads();
#pragma unroll
    for (int i = 0; i < 4; i++){
      int r  = srow + i*8;
      int ce = ((sch ^ (r & 7)) * 8);
      gld16(A + (size_t)(m0 + r) * K + k0 + ce, &As[w*2048 + i*512]);
      gld16(B + (size_t)(n0 + r) * K + k0 + ce, &Bs[w*2048 + i*512]);
    }
    __syncthreads();
#pragma unroll
    for (int kc = 0; kc < 2; kc++){
      v8s af[4], bf[4];
#pragma unroll
      for (int i = 0; i < 4; i++){
        int r = wr*64 + i*16 + mm;
        af[i] = *(const v8s*)&As[r*64 + (((kc*4 + g) ^ (r & 7)) * 8)];
      }
#pragma unroll
      for (int j = 0; j < 4; j++){
        int r = wc*64 + j*16 + mm;
        bf[j] = *(const v8s*)&Bs[r*64 + (((kc*4 + g) ^ (r & 7)) * 8)];
      }
#pragma unroll
      for (int i = 0; i < 4; i++)
#pragma unroll
        for (int j = 0; j < 4; j++)
          acc[i][j] = __builtin_amdgcn_mfma_f32_16x16x32_bf16(af[i], bf[j], acc[i][j], 0, 0, 0);
    }
  }
  if (OUT_BF16){
    u16* C = (u16*)Cv;
#pragma unroll
    for (int i = 0; i < 4; i++)
#pragma unroll
      for (int j = 0; j < 4; j++)
#pragma unroll
        for (int r = 0; r < 4; r++)
          C[(size_t)(m0 + wr*64 + i*16 + g*4 + r) * N + n0 + wc*64 + j*16 + mm] = f2b(acc[i][j][r]);
  } else {
    float* C = (float*)Cv;
#pragma unroll
    for (int i = 0; i < 4; i++)
#pragma unroll
      for (int j = 0; j < 4; j++)
#pragma unroll
        for (int r = 0; r < 4; r++)
          C[(size_t)(m0 + wr*64 + i*16 + g*4 + r) * N + n0 + wc*64 + j*16 + mm] = acc[i][j][r];
  }
}

// rope for Q (blocks 0..8191) and K (8192..10239) in one launch; bf16 in/out
__global__ __launch_bounds__(256) void rope_all(const u16* __restrict__ QKVb,
    const float* __restrict__ cosb, const float* __restrict__ sinb,
    u16* __restrict__ Qbf, u16* __restrict__ Kbf)
{
  int b = blockIdx.x;
  int d, h, s;
  const u16* src; u16* dst;
  if (b < 8192){
    int idx = b * 256 + threadIdx.x;
    d = idx & 31; h = (idx >> 5) & 31; s = idx >> 10;
    src = QKVb + (size_t)s * 3072 + h * HD + d;
    dst = Qbf + ((size_t)h * S_LEN + s) * HD + d;
  } else {
    int idx = (b - 8192) * 256 + threadIdx.x;
    d = idx & 31; h = (idx >> 5) & 7; s = idx >> 8;
    src = QKVb + (size_t)s * 3072 + 2048 + h * HD + d;
    dst = Kbf + ((size_t)h * S_LEN + s) * HD + d;
  }
  float c1 = cosb[s * HD + d],      s1 = sinb[s * HD + d];
  float c2 = cosb[s * HD + d + 32], s2 = sinb[s * HD + d + 32];
  float x1 = b2f(src[0]), x2 = b2f(src[32]);
  dst[0]  = f2b(x1 * c1 - x2 * s1);
  dst[32] = f2b(x2 * c2 + x1 * s2);
}

// V bf16 rows (stride u16 elems, head h at col h*64) -> Vt bf16 (8, 64, S)
__global__ __launch_bounds__(256) void vtrans(const u16* __restrict__ Vb, int stride, u16* __restrict__ Vt)
{
  __shared__ u16 T[64][72];
  const int b = blockIdx.x;
  const int h = b >> 5;
  const int s0 = (b & 31) * 64;
  const int t = threadIdx.x;
#pragma unroll
  for (int i = 0; i < 4; i++){
    int u = t + i * 256;
    int r = u >> 4, c4 = (u & 15) * 4;
    uint2 v = *(const uint2*)&Vb[(size_t)(s0 + r) * stride + h * HD + c4];
    T[c4+0][r] = (u16)(v.x & 0xffff); T[c4+1][r] = (u16)(v.x >> 16);
    T[c4+2][r] = (u16)(v.y & 0xffff); T[c4+3][r] = (u16)(v.y >> 16);
  }
  __syncthreads();
#pragma unroll
  for (int i = 0; i < 2; i++){
    int u = t + i * 256;
    int d = u >> 3, ch = (u & 7) * 8;
    *(uint4*)&Vt[((size_t)h * HD + d) * S_LEN + s0 + ch] = *(const uint4*)&T[d][ch];
  }
}

// Fused differential flash attention, 8 waves/block:
// waves 0-3 = head hp, waves 4-7 = head hp+16, sharing K/V LDS tiles.
// Uniform-work blocks: block (p,hp) does q-tiles 31-p then p (33 k-iters total).
// Epilogue: head-b waves deposit Ob*lam/lb into fp32 LDS (overlaid on dead K bufs),
// head-a waves do diff + RMS + scale and write bf16 Ctx.
__global__ __launch_bounds__(512) void attn_fused(
    const u16* __restrict__ Qbf, const u16* __restrict__ Kbf, const u16* __restrict__ Vt,
    const float* __restrict__ lq1, const float* __restrict__ lk1,
    const float* __restrict__ lq2, const float* __restrict__ lk2,
    u16* __restrict__ Ctx)
{
  __shared__ __attribute__((aligned(16))) u16 SM[33792];   // 67584 B
  u16* QPa = SM;                 // 64 x 72 (Q then P, head a)
  u16* QPb = SM + 4608;          // 64 x 72 (head b)
  u16* Ksf = SM + 9216;          // Ksa[2] (2x 64x64) then Ksb[2]
  u16* Vs  = SM + 25600;         // 128 x 64
  float* OLDS = (float*)(SM + 9216);  // 64 x 128 fp32, overlays K bufs (epilogue only)

  const int p   = blockIdx.x;                 // 0..15
  const int hp  = blockIdx.y;                 // 0..15
  const int kva = hp >> 2, kvb = kva + 4;
  const int t   = threadIdx.x, w = t >> 6, lane = t & 63;
  const int hb  = w >> 2;                     // 0 = head a, 1 = head b
  const int wq  = w & 3;                      // q-row group
  const int mm  = lane & 15, g = lane >> 4, g8 = g * 8;
  const int sr  = t >> 3;                     // staging row 0..63
  const int sc  = t & 7;
  const int so  = sc * 8;
  const int x0  = ((g ^ (mm & 7)) * 8);
  const int x1  = (((g + 4) ^ (mm & 7)) * 8);

  u16* QP = hb ? QPb : QPa;

  float lp1 = lq1[lane] * lk1[lane];
  float lp2 = lq2[lane] * lk2[lane];
#pragma unroll
  for (int off = 1; off < 64; off <<= 1){
    lp1 += __shfl_xor(lp1, off);
    lp2 += __shfl_xor(lp2, off);
  }
  const float lam = __expf(lp1) - __expf(lp2) + LAMBDA_INIT;

  for (int seg = 0; seg < 2; seg++){
    const int qt = seg ? p : (31 - p);
    const int q0 = qt * 64;

    __syncthreads();   // prior segment fully done (incl. OLDS reads) before restage
    // issue K(0) into buffer 0; stage Q tiles with plain stores
    {
      int ce = ((sc ^ (sr & 7)) * 8);
      gld16(Kbf + ((size_t)kva * S_LEN + sr) * HD + ce, Ksf + (w*8)*64);
      gld16(Kbf + ((size_t)kvb * S_LEN + sr) * HD + ce, Ksf + 8192 + (w*8)*64);
    }
    *(uint4*)&QPa[sr*72 + so] = *(const uint4*)&Qbf[((size_t)hp        * S_LEN + q0 + sr) * HD + so];
    *(uint4*)&QPb[sr*72 + so] = *(const uint4*)&Qbf[((size_t)(hp + 16) * S_LEN + q0 + sr) * HD + so];
    __syncthreads();   // Q visible, K(0) drained
    v8s qa0 = *(const v8s*)&QP[(wq*16 + mm)*72 + g8];
    v8s qa1 = *(const v8s*)&QP[(wq*16 + mm)*72 + 32 + g8];

    v4f O[8];
#pragma unroll
    for (int n = 0; n < 8; n++) O[n] = (v4f){0.f,0.f,0.f,0.f};
    float l[4] = {0.f,0.f,0.f,0.f};

    for (int k0 = 0; k0 <= q0; k0 += 64){
      const int cur = (k0 >> 6) & 1;
      if (k0) __syncthreads();          // prior PV done with Vs / prior QK done with Ks[cur^1]
      // issue V(k0) — drains behind QK+softmax
#pragma unroll
      for (int i = 0; i < 2; i++){
        int head = i ? kvb : kva;
        int ce   = ((sc ^ (sr & 7)) * 8);
        gld16(Vt + ((size_t)head * HD + sr) * S_LEN + k0 + ce, Vs + (w*8 + i*64)*64);
      }
      // prefetch K(k0+64) into other buffer
      if (k0 + 64 <= q0){
        int ce = ((sc ^ (sr & 7)) * 8);
        gld16(Kbf + ((size_t)kva * S_LEN + k0 + 64 + sr) * HD + ce, Ksf + (cur^1)*4096 + (w*8)*64);
        gld16(Kbf + ((size_t)kvb * S_LEN + k0 + 64 + sr) * HD + ce, Ksf + 8192 + (cur^1)*4096 + (w*8)*64);
      }

      const u16* Kh = Ksf + hb*8192 + cur*4096;
      const bool dg = (k0 == q0);
      v4f S[4];
#pragma unroll
      for (int n = 0; n < 4; n++){
        int row = n*16 + mm;
        v8s kb0 = *(const v8s*)&Kh[row*64 + x0];
        v8s kb1 = *(const v8s*)&Kh[row*64 + x1];
        v4f z = (v4f){0.f,0.f,0.f,0.f};
        z = __builtin_amdgcn_mfma_f32_16x16x32_bf16(qa0, kb0, z, 0, 0, 0);
        z = __builtin_amdgcn_mfma_f32_16x16x32_bf16(qa1, kb1, z, 0, 0, 0);
        S[n] = z;
      }
#pragma unroll
      for (int n = 0; n < 4; n++)
#pragma unroll
        for (int r = 0; r < 4; r++){
          float pe = __expf(S[n][r] * 0.125f);
          if (dg && (n*16 + mm > wq*16 + g*4 + r)) pe = 0.f;
          l[r] += pe;
          QP[(wq*16 + g*4 + r)*72 + n*16 + mm] = f2b(pe);
        }
      __syncthreads();                  // V staged (issued at iter top)
      v8s pa0 = *(const v8s*)&QP[(wq*16 + mm)*72 + g8];
      v8s pa1 = *(const v8s*)&QP[(wq*16 + mm)*72 + 32 + g8];
#pragma unroll
      for (int n = 0; n < 8; n++){
        int row = n*16 + mm;
        v8s vb0 = *(const v8s*)&Vs[row*64 + x0];
        v8s vb1 = *(const v8s*)&Vs[row*64 + x1];
        O[n] = __builtin_amdgcn_mfma_f32_16x16x32_bf16(pa0, vb0, O[n], 0, 0, 0);
        O[n] = __builtin_amdgcn_mfma_f32_16x16x32_bf16(pa1, vb1, O[n], 0, 0, 0);
      }
    }

    // ---- epilogue for this segment ----
#pragma unroll
    for (int off = 1; off < 16; off <<= 1)
#pragma unroll
      for (int r = 0; r < 4; r++)
        l[r] += __shfl_xor(l[r], off);
    float il[4];
#pragma unroll
    for (int r = 0; r < 4; r++) il[r] = hb ? (lam / l[r]) : (1.0f / l[r]);

    __syncthreads();   // all QK reads of Ks done; OLDS may overwrite K bufs
    if (hb){
#pragma unroll
      for (int n = 0; n < 8; n++)
#pragma unroll
        for (int r = 0; r < 4; r++)
          OLDS[(wq*16 + g*4 + r)*128 + n*16 + mm] = O[n][r] * il[r];
    }
    __syncthreads();
    if (!hb){
      float av[8][4];
      float ss[4] = {0.f,0.f,0.f,0.f};
#pragma unroll
      for (int n = 0; n < 8; n++)
#pragma unroll
        for (int r = 0; r < 4; r++){
          float a = O[n][r] * il[r] - OLDS[(wq*16 + g*4 + r)*128 + n*16 + mm];
          av[n][r] = a;
          ss[r] += a * a;
        }
#pragma unroll
      for (int off = 1; off < 16; off <<= 1)
#pragma unroll
        for (int r = 0; r < 4; r++)
          ss[r] += __shfl_xor(ss[r], off);
      float rv[4];
#pragma unroll
      for (int r = 0; r < 4; r++)
        rv[r] = rsqrtf(ss[r] * (1.0f/128.0f) + 1e-6f) * ONE_MINUS_LI;
#pragma unroll
      for (int n = 0; n < 8; n++)
#pragma unroll
        for (int r = 0; r < 4; r++){
          int srow = q0 + wq*16 + g*4 + r;
          Ctx[(size_t)srow * HID + hp * DVV + n*16 + mm] = f2b(av[n][r] * rv[r]);
        }
    }
  }
}

extern "C" void kernel_launch(void* const* d_in, const int* in_sizes, int n_in,
                              void* d_out, int out_size, void* d_ws, size_t ws_size,
                              hipStream_t stream)
{
  (void)in_sizes; (void)n_in; (void)out_size; (void)ws_size;
  const float* hs   = (const float*)d_in[0];
  const float* cosb = (const float*)d_in[1];
  const float* sinb = (const float*)d_in[2];
  const float* Wq   = (const float*)d_in[3];
  const float* Wk   = (const float*)d_in[4];
  const float* Wv   = (const float*)d_in[5];
  const float* Wo   = (const float*)d_in[6];
  const float* lq1  = (const float*)d_in[7];
  const float* lk1  = (const float*)d_in[8];
  const float* lq2  = (const float*)d_in[9];
  const float* lk2  = (const float*)d_in[10];

  char* ws = (char*)d_ws;
  u16* hsb   = (u16*)(ws);                   // [0,8) MB bf16 hs
  u16* Wqkvb = (u16*)(ws + (8u  << 20));     // [8,20) bf16 [Wq;Wk;Wv] 3072x2048
  u16* QKVb  = (u16*)(ws + (20u << 20));     // [20,32) bf16 (S,3072)
  u16* Ctx   = (u16*)(ws + (20u << 20));     // [20,28) overlays QKVb after rope/vtrans
  u16* Wob   = (u16*)(ws + (32u << 20));     // [32,40) bf16 Wo
  u16* Kbf   = (u16*)(ws + (44u << 20));     // [44,46) bf16 (8,S,64)
  u16* Vt    = (u16*)(ws + (46u << 20));     // [46,48) bf16 (8,64,S)
  u16* Qbf   = (u16*)(ws + (48u << 20));     // [48,56) bf16 (32,S,64)

  cast5<<<7168, 256, 0, stream>>>(hs, Wq, Wk, Wv, Wo, hsb, Wqkvb, Wob);
  gemm_bf16<1><<<dim3(24, 16), 256, 0, stream>>>(hsb, Wqkvb, QKVb, S_LEN, 3072, HID);
  rope_all<<<10240, 256, 0, stream>>>(QKVb, cosb, sinb, Qbf, Kbf);
  vtrans<<<NKV * (S_LEN/64), 256, 0, stream>>>(QKVb + 2560, 3072, Vt);
  attn_fused<<<dim3(16, 16), 512, 0, stream>>>(Qbf, Kbf, Vt, lq1, lk1, lq2, lk2, Ctx);
  gemm_bf16<0><<<dim3(16, 16), 256, 0, stream>>>(Ctx, Wob, (float*)d_out, S_LEN, 2048, HID);
}